// Round 4
// baseline (1167.266 us; speedup 1.0000x reference)
//
#include <hip/hip_runtime.h>
#include <hip/hip_fp16.h>

#define NN 100000
#define NE 3200000
#define NG 1024
#define NP 100352            // NN padded to multiple of 256
#define BUCK 64              // dst nodes per bucket
#define NBUCK 1563           // ceil(NN/64)
#define NBLK 256
#define CHUNK ((NE + NBLK - 1) / NBLK)
#define SCAN_STRIDE 7        // ceil(NBUCK/256)

// ---------- fp16 pack helpers ----------
static __device__ inline uint2 pack4(float a, float b, float c, float d) {
    __half2 lo = __floats2half2_rn(a, b);
    __half2 hi = __floats2half2_rn(c, d);
    uint2 u;
    u.x = *reinterpret_cast<unsigned int*>(&lo);
    u.y = *reinterpret_cast<unsigned int*>(&hi);
    return u;
}

// ---- k1: per-bucket edge histogram (64-dst buckets) ----
__global__ void hist_buckets(const int* __restrict__ dst, int* __restrict__ bcnt) {
    __shared__ int sm[NBUCK];
    int tid = threadIdx.x;
    for (int i = tid; i < NBUCK; i += 256) sm[i] = 0;
    __syncthreads();
    int s = blockIdx.x * CHUNK, e = min(NE, s + CHUNK);
    for (int i = s + tid; i < e; i += 256) atomicAdd(&sm[dst[i] >> 6], 1);
    __syncthreads();
    for (int i = tid; i < NBUCK; i += 256)
        if (sm[i]) atomicAdd(&bcnt[i], sm[i]);
}

// ---- k2: exclusive scan of 1563 bucket counts (1 block, 7 elems/thread) ----
__global__ void scan_buckets(const int* __restrict__ bcnt, int* __restrict__ bbase) {
    __shared__ int tmp[256];
    int tid = threadIdx.x;
    int local[SCAN_STRIDE];
    int s = 0;
#pragma unroll
    for (int j = 0; j < SCAN_STRIDE; j++) {
        int idx = tid * SCAN_STRIDE + j;
        int v = (idx < NBUCK) ? bcnt[idx] : 0;
        local[j] = s;               // exclusive within this thread's chunk
        s += v;
    }
    tmp[tid] = s;
    __syncthreads();
    for (int off = 1; off < 256; off <<= 1) {
        int t = (tid >= off) ? tmp[tid - off] : 0;
        __syncthreads();
        tmp[tid] += t;
        __syncthreads();
    }
    int base = tmp[tid] - s;        // exclusive prefix of chunk
#pragma unroll
    for (int j = 0; j < SCAN_STRIDE; j++) {
        int idx = tid * SCAN_STRIDE + j;
        if (idx < NBUCK) bbase[idx] = base + local[j];
    }
}

// ---- k3: partition edges into bucket regions, packed (dst&63)<<17 | src ----
__global__ void partition(const int* __restrict__ src, const int* __restrict__ dst,
                          const int* __restrict__ bbase, int* __restrict__ bfill,
                          int* __restrict__ part) {
    __shared__ int smh[NBUCK];
    __shared__ int smc[NBUCK];
    int tid = threadIdx.x;
    for (int i = tid; i < NBUCK; i += 256) smh[i] = 0;
    __syncthreads();
    int s = blockIdx.x * CHUNK, e = min(NE, s + CHUNK);
    for (int i = s + tid; i < e; i += 256) atomicAdd(&smh[dst[i] >> 6], 1);
    __syncthreads();
    for (int i = tid; i < NBUCK; i += 256) {
        int c = smh[i];
        smc[i] = c ? (bbase[i] + atomicAdd(&bfill[i], c)) : 0;
    }
    __syncthreads();
    for (int i = s + tid; i < e; i += 256) {
        int d = dst[i];
        int b = d >> 6;
        int p = atomicAdd(&smc[b], 1);
        part[p] = src[i] | ((d & 63) << 17);
    }
}

// ---- k4: per-bucket degree histogram -> dis ----
__global__ void deg_dis(const int* __restrict__ part, const int* __restrict__ bbase,
                        const int* __restrict__ bcnt, float* __restrict__ dis) {
    __shared__ int smc[BUCK];
    int b = blockIdx.x, tid = threadIdx.x;
    if (tid < BUCK) smc[tid] = 0;
    __syncthreads();
    int base = bbase[b], m = bcnt[b];
    for (int i = base + tid; i < base + m; i += 256) atomicAdd(&smc[part[i] >> 17], 1);
    __syncthreads();
    int n = b * BUCK + tid;
    if (tid < BUCK && n < NN) dis[n] = rsqrtf((float)smc[tid] + 1.0f);
}

// ---- embed one-hot + transform by Wg0, premultiply dis, fp16 out ----
__global__ void embed_tf0(const int* __restrict__ types, const int* __restrict__ pos,
                          const float* __restrict__ W1, const float* __restrict__ b1,
                          const float* __restrict__ W2, const float* __restrict__ b2,
                          const float* __restrict__ Wg0, const float* __restrict__ dis,
                          uint2* __restrict__ hs) {
    __shared__ float sW[32 * 16];
    int tid = threadIdx.x;
    sW[tid] = Wg0[tid];
    sW[tid + 256] = Wg0[tid + 256];
    __syncthreads();
    int n = blockIdx.x * 256 + tid;
    if (n >= NN) return;
    int ty = types[n], pp = pos[n];
    float z[32];
#pragma unroll
    for (int j = 0; j < 16; j++) z[j] = W1[ty * 16 + j] + b1[j];
#pragma unroll
    for (int j = 0; j < 16; j++) z[16 + j] = W2[pp * 16 + j] + b2[j];
    float dn = dis[n];
    uint2 o[4];
#pragma unroll
    for (int q = 0; q < 4; q++) {
        float hv[4];
#pragma unroll
        for (int m = 0; m < 4; m++) {
            float a = 0.0f;
#pragma unroll
            for (int k = 0; k < 32; k++) a += z[k] * sW[k * 16 + q * 4 + m];
            hv[m] = a * dn;
        }
        o[q] = pack4(hv[0], hv[1], hv[2], hv[3]);
    }
#pragma unroll
    for (int q = 0; q < 4; q++) hs[(size_t)n * 4 + q] = o[q];
}

// ---- edge-parallel aggregation: one block OWNS one 64-dst bucket ----
// LDS fp32 acc[64][17]; merge is plain coalesced float4 stores (NO global atomics).
__global__ __launch_bounds__(256, 4) void agg_edge(
        const uint2* __restrict__ hs, const int* __restrict__ part,
        const int* __restrict__ bbase, const int* __restrict__ bcnt,
        float* __restrict__ zagg) {
    __shared__ float acc[BUCK * 17];
    int tid = threadIdx.x;
    int b = blockIdx.x;
    for (int i = tid; i < BUCK * 17; i += 256) acc[i] = 0.f;
    __syncthreads();
    int base = bbase[b], m = bcnt[b];
    int i = base + tid;
    int end = base + m;

    // accumulate one edge's 16 features into LDS (addrspace(3) guaranteed: acc direct)
#define ACCUM_EDGE(P, A, B)                                                   \
    do {                                                                      \
        int _l = ((P) >> 17) * 17;                                            \
        const __half2* _h = reinterpret_cast<const __half2*>(&(A));           \
        const __half2* _g = reinterpret_cast<const __half2*>(&(B));           \
        float2 _f0 = __half22float2(_h[0]), _f1 = __half22float2(_h[1]);      \
        float2 _f2 = __half22float2(_h[2]), _f3 = __half22float2(_h[3]);      \
        float2 _f4 = __half22float2(_g[0]), _f5 = __half22float2(_g[1]);      \
        float2 _f6 = __half22float2(_g[2]), _f7 = __half22float2(_g[3]);      \
        atomicAdd(&acc[_l + 0], _f0.x);  atomicAdd(&acc[_l + 1], _f0.y);      \
        atomicAdd(&acc[_l + 2], _f1.x);  atomicAdd(&acc[_l + 3], _f1.y);      \
        atomicAdd(&acc[_l + 4], _f2.x);  atomicAdd(&acc[_l + 5], _f2.y);      \
        atomicAdd(&acc[_l + 6], _f3.x);  atomicAdd(&acc[_l + 7], _f3.y);      \
        atomicAdd(&acc[_l + 8], _f4.x);  atomicAdd(&acc[_l + 9], _f4.y);      \
        atomicAdd(&acc[_l + 10], _f5.x); atomicAdd(&acc[_l + 11], _f5.y);     \
        atomicAdd(&acc[_l + 12], _f6.x); atomicAdd(&acc[_l + 13], _f6.y);     \
        atomicAdd(&acc[_l + 14], _f7.x); atomicAdd(&acc[_l + 15], _f7.y);     \
    } while (0)

    // 4x unrolled main: 4 part loads, 8 gathers in flight, then 64 LDS atomics.
    for (; i + 768 < end; i += 1024) {
        int p0 = part[i];
        int p1 = part[i + 256];
        int p2 = part[i + 512];
        int p3 = part[i + 768];
        const uint4* q0 = (const uint4*)(hs + (size_t)(p0 & 0x1FFFF) * 4);
        const uint4* q1 = (const uint4*)(hs + (size_t)(p1 & 0x1FFFF) * 4);
        const uint4* q2 = (const uint4*)(hs + (size_t)(p2 & 0x1FFFF) * 4);
        const uint4* q3 = (const uint4*)(hs + (size_t)(p3 & 0x1FFFF) * 4);
        uint4 a0 = q0[0], b0 = q0[1];
        uint4 a1 = q1[0], b1 = q1[1];
        uint4 a2 = q2[0], b2 = q2[1];
        uint4 a3 = q3[0], b3 = q3[1];
        ACCUM_EDGE(p0, a0, b0);
        ACCUM_EDGE(p1, a1, b1);
        ACCUM_EDGE(p2, a2, b2);
        ACCUM_EDGE(p3, a3, b3);
    }
    for (; i < end; i += 256) {
        int p = part[i];
        const uint4* q = (const uint4*)(hs + (size_t)(p & 0x1FFFF) * 4);
        uint4 a = q[0], bb = q[1];
        ACCUM_EDGE(p, a, bb);
    }
#undef ACCUM_EDGE
    __syncthreads();

    // exclusive-owner merge: 64 nodes x 16 feats = 1024 floats = 256 float4 stores
    int j = tid >> 2, k0 = (tid & 3) << 2;
    float4 o = make_float4(acc[j * 17 + k0], acc[j * 17 + k0 + 1],
                           acc[j * 17 + k0 + 2], acc[j * 17 + k0 + 3]);
    ((float4*)zagg)[(size_t)b * 256 + tid] = o;
}

// ---- node-parallel: self loop + bias (+relu) + 16x16 transform + fp16 repack ----
// zagg is fully overwritten by agg_edge each layer -> no re-zero needed.
template <int RELU, int FUSE_POOL>
__global__ void tf_node(const float* __restrict__ zagg, const uint2* __restrict__ hs,
                        const float* __restrict__ dis, const float* __restrict__ bias,
                        const float* __restrict__ Wn, uint2* __restrict__ hs_out,
                        const int* __restrict__ batch, float* __restrict__ pool,
                        int* __restrict__ gcnt) {
    __shared__ float sW[256];
    int tid = threadIdx.x;
    if (!FUSE_POOL) {
        sW[tid] = Wn[tid];
        __syncthreads();
    }
    int n = blockIdx.x * 256 + tid;
    if (n >= NN) return;
    const float4* zp = (const float4*)(zagg + (size_t)n * 16);
    float4 z0 = zp[0], z1 = zp[1], z2 = zp[2], z3 = zp[3];
    const uint4* hp = (const uint4*)(hs + (size_t)n * 4);
    uint4 ha = hp[0], hb = hp[1];
    float dn = dis[n];
    const __half2* h = reinterpret_cast<const __half2*>(&ha);
    const __half2* g = reinterpret_cast<const __half2*>(&hb);
    float2 s0 = __half22float2(h[0]), s1 = __half22float2(h[1]);
    float2 s2 = __half22float2(h[2]), s3 = __half22float2(h[3]);
    float2 s4 = __half22float2(g[0]), s5 = __half22float2(g[1]);
    float2 s6 = __half22float2(g[2]), s7 = __half22float2(g[3]);
    float z[16];
    z[0] = z0.x + s0.x;  z[1] = z0.y + s0.y;  z[2] = z0.z + s1.x;  z[3] = z0.w + s1.y;
    z[4] = z1.x + s2.x;  z[5] = z1.y + s2.y;  z[6] = z1.z + s3.x;  z[7] = z1.w + s3.y;
    z[8] = z2.x + s4.x;  z[9] = z2.y + s4.y;  z[10] = z2.z + s5.x; z[11] = z2.w + s5.y;
    z[12] = z3.x + s6.x; z[13] = z3.y + s6.y; z[14] = z3.z + s7.x; z[15] = z3.w + s7.y;
#pragma unroll
    for (int j = 0; j < 16; j++) {
        z[j] = fmaf(z[j], dn, bias[j]);
        if (RELU) z[j] = fmaxf(z[j], 0.f);
    }
    if (FUSE_POOL) {
        float sacc = 0.f;
#pragma unroll
        for (int j = 0; j < 16; j++) sacc += z[j] * Wn[j];
        int gg = batch[n];
        atomicAdd(&pool[gg], sacc);
        atomicAdd(&gcnt[gg], 1);
    } else {
        uint2 o[4];
#pragma unroll
        for (int q = 0; q < 4; q++) {
            float hv[4];
#pragma unroll
            for (int mm = 0; mm < 4; mm++) {
                float a = 0.f;
#pragma unroll
                for (int k = 0; k < 16; k++) a += z[k] * sW[k * 16 + q * 4 + mm];
                hv[mm] = a * dn;
            }
            o[q] = pack4(hv[0], hv[1], hv[2], hv[3]);
        }
        uint2* op = hs_out + (size_t)n * 4;
#pragma unroll
        for (int q = 0; q < 4; q++) op[q] = o[q];
    }
}

__global__ void finalize(const float* __restrict__ pool, const int* __restrict__ gcnt,
                         const float* __restrict__ bo, float* __restrict__ out) {
    int g = blockIdx.x * 256 + threadIdx.x;
    if (g < NG) {
        float c = fmaxf((float)gcnt[g], 1.0f);
        out[g] = pool[g] / c + bo[0];
    }
}

extern "C" void kernel_launch(void* const* d_in, const int* in_sizes, int n_in,
                              void* d_out, int out_size, void* d_ws, size_t ws_size,
                              hipStream_t stream) {
    const int*   types = (const int*)d_in[0];
    const int*   pos   = (const int*)d_in[1];
    const int*   ei    = (const int*)d_in[2];   // [2, E]: src then dst
    const int*   batch = (const int*)d_in[3];
    const float* W1  = (const float*)d_in[4];
    const float* b1  = (const float*)d_in[5];
    const float* W2  = (const float*)d_in[6];
    const float* b2  = (const float*)d_in[7];
    const float* Wg0 = (const float*)d_in[8];
    const float* bg0 = (const float*)d_in[9];
    const float* Wg1 = (const float*)d_in[10];
    const float* bg1 = (const float*)d_in[11];
    const float* Wg2 = (const float*)d_in[12];
    const float* bg2 = (const float*)d_in[13];
    const float* Wo  = (const float*)d_in[14];
    const float* bo  = (const float*)d_in[15];
    float* out = (float*)d_out;

    const int* esrc = ei;
    const int* edst = ei + NE;

    // ---- workspace layout (ints), all 16B-aligned ----
    int*   bcnt  = (int*)d_ws;                   // 2048 (zeroed)
    int*   bfill = bcnt + 2048;                  // 2048 (zeroed)
    float* pool  = (float*)(bfill + 2048);       // 1024 (zeroed)
    int*   gcnt  = (int*)(pool + NG);            // 1024 (zeroed)
    int*   bbase = gcnt + NG;                    // 2048
    float* dis   = (float*)(bbase + 2048);       // NP floats
    int*   part  = (int*)(dis + NP);             // NE  (persists across layers)
    float* zagg  = (float*)(part + NE);          // NP*16 floats (fp32 edge sums)
    uint2* hsA   = (uint2*)(zagg + (size_t)NP * 16);  // NP*4 uint2 = 3.2 MB
    uint2* hsB   = (uint2*)((int*)hsA + NP * 8);      // 3.2 MB
    (void)ws_size; (void)n_in; (void)in_sizes; (void)out_size;

    hipMemsetAsync(d_ws, 0, (size_t)(4096 + 2 * NG) * sizeof(int), stream);

    const int NB256 = (NN + 255) / 256;          // 391

    hist_buckets<<<NBLK, 256, 0, stream>>>(edst, bcnt);
    scan_buckets<<<1, 256, 0, stream>>>(bcnt, bbase);
    partition<<<NBLK, 256, 0, stream>>>(esrc, edst, bbase, bfill, part);
    deg_dis<<<NBUCK, 256, 0, stream>>>(part, bbase, bcnt, dis);

    // layer 0 input: hs0 = (z0 @ Wg0) * dis  (fp16)
    embed_tf0<<<NB256, 256, 0, stream>>>(types, pos, W1, b1, W2, b2, Wg0, dis, hsA);

    // layer 0: edge-parallel agg -> zagg ; node pass: +self +bg0, relu, @Wg1 -> hsB
    agg_edge<<<NBUCK, 256, 0, stream>>>(hsA, part, bbase, bcnt, zagg);
    tf_node<1, 0><<<NB256, 256, 0, stream>>>(zagg, hsA, dis, bg0, Wg1, hsB,
                                             batch, pool, gcnt);
    // layer 1
    agg_edge<<<NBUCK, 256, 0, stream>>>(hsB, part, bbase, bcnt, zagg);
    tf_node<1, 0><<<NB256, 256, 0, stream>>>(zagg, hsB, dis, bg1, Wg2, hsA,
                                             batch, pool, gcnt);
    // layer 2: agg + (no relu) + Wo dot + pool
    agg_edge<<<NBUCK, 256, 0, stream>>>(hsA, part, bbase, bcnt, zagg);
    tf_node<0, 1><<<NB256, 256, 0, stream>>>(zagg, hsA, dis, bg2, Wo, hsB /*unused*/,
                                             batch, pool, gcnt);

    finalize<<<(NG + 255) / 256, 256, 0, stream>>>(pool, gcnt, bo, out);
}

// Round 5
// 1097.039 us; speedup vs baseline: 1.0640x; 1.0640x over previous
//
#include <hip/hip_runtime.h>
#include <hip/hip_fp16.h>

#define NN 100000
#define NE 3200000
#define NG 1024
#define NP 100352            // NN padded to multiple of 256
#define BUCK 64              // dst nodes per bucket
#define NBUCK 1563           // ceil(NN/64)
#define NBLK 256
#define CHUNK ((NE + NBLK - 1) / NBLK)
#define SCAN_STRIDE 7        // ceil(NBUCK/256)

// ---------- fp16 pack helpers ----------
static __device__ inline uint2 pack4(float a, float b, float c, float d) {
    __half2 lo = __floats2half2_rn(a, b);
    __half2 hi = __floats2half2_rn(c, d);
    uint2 u;
    u.x = *reinterpret_cast<unsigned int*>(&lo);
    u.y = *reinterpret_cast<unsigned int*>(&hi);
    return u;
}
static __device__ inline float4 shfl_xor4(float4 v, int m) {
    float4 r;
    r.x = __shfl_xor(v.x, m); r.y = __shfl_xor(v.y, m);
    r.z = __shfl_xor(v.z, m); r.w = __shfl_xor(v.w, m);
    return r;
}

// ---- k1: per-bucket edge histogram (64-dst buckets) ----
__global__ void hist_buckets(const int* __restrict__ dst, int* __restrict__ bcnt) {
    __shared__ int sm[NBUCK];
    int tid = threadIdx.x;
    for (int i = tid; i < NBUCK; i += 256) sm[i] = 0;
    __syncthreads();
    int s = blockIdx.x * CHUNK, e = min(NE, s + CHUNK);
    for (int i = s + tid; i < e; i += 256) atomicAdd(&sm[dst[i] >> 6], 1);
    __syncthreads();
    for (int i = tid; i < NBUCK; i += 256)
        if (sm[i]) atomicAdd(&bcnt[i], sm[i]);
}

// ---- k2: exclusive scan of 1563 bucket counts (1 block, 7 elems/thread) ----
__global__ void scan_buckets(const int* __restrict__ bcnt, int* __restrict__ bbase) {
    __shared__ int tmp[256];
    int tid = threadIdx.x;
    int local[SCAN_STRIDE];
    int s = 0;
#pragma unroll
    for (int j = 0; j < SCAN_STRIDE; j++) {
        int idx = tid * SCAN_STRIDE + j;
        int v = (idx < NBUCK) ? bcnt[idx] : 0;
        local[j] = s;               // exclusive within this thread's chunk
        s += v;
    }
    tmp[tid] = s;
    __syncthreads();
    for (int off = 1; off < 256; off <<= 1) {
        int t = (tid >= off) ? tmp[tid - off] : 0;
        __syncthreads();
        tmp[tid] += t;
        __syncthreads();
    }
    int base = tmp[tid] - s;        // exclusive prefix of chunk
#pragma unroll
    for (int j = 0; j < SCAN_STRIDE; j++) {
        int idx = tid * SCAN_STRIDE + j;
        if (idx < NBUCK) bbase[idx] = base + local[j];
    }
}

// ---- k3: partition edges into bucket regions, packed (dst&63)<<17 | src ----
__global__ void partition(const int* __restrict__ src, const int* __restrict__ dst,
                          const int* __restrict__ bbase, int* __restrict__ bfill,
                          int* __restrict__ part) {
    __shared__ int smh[NBUCK];
    __shared__ int smc[NBUCK];
    int tid = threadIdx.x;
    for (int i = tid; i < NBUCK; i += 256) smh[i] = 0;
    __syncthreads();
    int s = blockIdx.x * CHUNK, e = min(NE, s + CHUNK);
    for (int i = s + tid; i < e; i += 256) atomicAdd(&smh[dst[i] >> 6], 1);
    __syncthreads();
    for (int i = tid; i < NBUCK; i += 256) {
        int c = smh[i];
        smc[i] = c ? (bbase[i] + atomicAdd(&bfill[i], c)) : 0;
    }
    __syncthreads();
    for (int i = s + tid; i < e; i += 256) {
        int d = dst[i];
        int b = d >> 6;
        int p = atomicAdd(&smc[b], 1);
        part[p] = src[i] | ((d & 63) << 17);
    }
}

// ---- k4: per-bucket degree histogram -> dis ----
__global__ void deg_dis(const int* __restrict__ part, const int* __restrict__ bbase,
                        const int* __restrict__ bcnt, float* __restrict__ dis) {
    __shared__ int smc[BUCK];
    int b = blockIdx.x, tid = threadIdx.x;
    if (tid < BUCK) smc[tid] = 0;
    __syncthreads();
    int base = bbase[b], m = bcnt[b];
    for (int i = base + tid; i < base + m; i += 256) atomicAdd(&smc[part[i] >> 17], 1);
    __syncthreads();
    int n = b * BUCK + tid;
    if (tid < BUCK && n < NN) dis[n] = rsqrtf((float)smc[tid] + 1.0f);
}

// ---- embed one-hot + transform by Wg0, premultiply dis, fp16 out ----
__global__ void embed_tf0(const int* __restrict__ types, const int* __restrict__ pos,
                          const float* __restrict__ W1, const float* __restrict__ b1,
                          const float* __restrict__ W2, const float* __restrict__ b2,
                          const float* __restrict__ Wg0, const float* __restrict__ dis,
                          uint2* __restrict__ hs) {
    __shared__ float sW[32 * 16];
    int tid = threadIdx.x;
    sW[tid] = Wg0[tid];
    sW[tid + 256] = Wg0[tid + 256];
    __syncthreads();
    int n = blockIdx.x * 256 + tid;
    if (n >= NN) return;
    int ty = types[n], pp = pos[n];
    float z[32];
#pragma unroll
    for (int j = 0; j < 16; j++) z[j] = W1[ty * 16 + j] + b1[j];
#pragma unroll
    for (int j = 0; j < 16; j++) z[16 + j] = W2[pp * 16 + j] + b2[j];
    float dn = dis[n];
    uint2 o[4];
#pragma unroll
    for (int q = 0; q < 4; q++) {
        float hv[4];
#pragma unroll
        for (int m = 0; m < 4; m++) {
            float a = 0.0f;
#pragma unroll
            for (int k = 0; k < 32; k++) a += z[k] * sW[k * 16 + q * 4 + m];
            hv[m] = a * dn;
        }
        o[q] = pack4(hv[0], hv[1], hv[2], hv[3]);
    }
#pragma unroll
    for (int q = 0; q < 4; q++) hs[(size_t)n * 4 + q] = o[q];
}

// ---- fused edge-parallel aggregation + node finish; one block OWNS one 64-dst bucket ----
// Accumulation uses unsafeAtomicAdd -> hardware ds_add_f32 (fire-and-forget),
// NOT the CAS loop that safe atomicAdd(float) lowers to (rounds 3/4 post-mortem).
template <int RELU, int FUSE_POOL>
__global__ __launch_bounds__(256, 4) void agg_fused(
        const uint2* __restrict__ hs, const int* __restrict__ part,
        const int* __restrict__ bbase, const int* __restrict__ bcnt,
        const float* __restrict__ dis, const float* __restrict__ bias,
        const float* __restrict__ Wn, uint2* __restrict__ hs_out,
        const int* __restrict__ batch, float* __restrict__ pool,
        int* __restrict__ gcnt) {
    __shared__ float acc[BUCK * 17];
    __shared__ float sW[256];
    int tid = threadIdx.x;
    int b = blockIdx.x;
    if (!FUSE_POOL) sW[tid] = Wn[tid];
    for (int i = tid; i < BUCK * 17; i += 256) acc[i] = 0.f;
    __syncthreads();
    int base = bbase[b], m = bcnt[b];
    int i = base + tid;
    int end = base + m;

#define ACCUM_EDGE(P, A, B)                                                       \
    do {                                                                          \
        float* _ap = &acc[((P) >> 17) * 17];                                      \
        const __half2* _h = reinterpret_cast<const __half2*>(&(A));               \
        const __half2* _g = reinterpret_cast<const __half2*>(&(B));               \
        float2 _f0 = __half22float2(_h[0]), _f1 = __half22float2(_h[1]);          \
        float2 _f2 = __half22float2(_h[2]), _f3 = __half22float2(_h[3]);          \
        float2 _f4 = __half22float2(_g[0]), _f5 = __half22float2(_g[1]);          \
        float2 _f6 = __half22float2(_g[2]), _f7 = __half22float2(_g[3]);          \
        unsafeAtomicAdd(_ap + 0, _f0.x);  unsafeAtomicAdd(_ap + 1, _f0.y);        \
        unsafeAtomicAdd(_ap + 2, _f1.x);  unsafeAtomicAdd(_ap + 3, _f1.y);        \
        unsafeAtomicAdd(_ap + 4, _f2.x);  unsafeAtomicAdd(_ap + 5, _f2.y);        \
        unsafeAtomicAdd(_ap + 6, _f3.x);  unsafeAtomicAdd(_ap + 7, _f3.y);        \
        unsafeAtomicAdd(_ap + 8, _f4.x);  unsafeAtomicAdd(_ap + 9, _f4.y);        \
        unsafeAtomicAdd(_ap + 10, _f5.x); unsafeAtomicAdd(_ap + 11, _f5.y);       \
        unsafeAtomicAdd(_ap + 12, _f6.x); unsafeAtomicAdd(_ap + 13, _f6.y);       \
        unsafeAtomicAdd(_ap + 14, _f7.x); unsafeAtomicAdd(_ap + 15, _f7.y);       \
    } while (0)

    // 4x unrolled main: 4 part loads, 8 gathers in flight, then 64 ds_add_f32.
    for (; i + 768 < end; i += 1024) {
        int p0 = part[i];
        int p1 = part[i + 256];
        int p2 = part[i + 512];
        int p3 = part[i + 768];
        const uint4* q0 = (const uint4*)(hs + (size_t)(p0 & 0x1FFFF) * 4);
        const uint4* q1 = (const uint4*)(hs + (size_t)(p1 & 0x1FFFF) * 4);
        const uint4* q2 = (const uint4*)(hs + (size_t)(p2 & 0x1FFFF) * 4);
        const uint4* q3 = (const uint4*)(hs + (size_t)(p3 & 0x1FFFF) * 4);
        uint4 a0 = q0[0], b0 = q0[1];
        uint4 a1 = q1[0], b1 = q1[1];
        uint4 a2 = q2[0], b2 = q2[1];
        uint4 a3 = q3[0], b3 = q3[1];
        ACCUM_EDGE(p0, a0, b0);
        ACCUM_EDGE(p1, a1, b1);
        ACCUM_EDGE(p2, a2, b2);
        ACCUM_EDGE(p3, a3, b3);
    }
    for (; i < end; i += 256) {
        int p = part[i];
        const uint4* q = (const uint4*)(hs + (size_t)(p & 0x1FFFF) * 4);
        uint4 a = q[0], bb = q[1];
        ACCUM_EDGE(p, a, bb);
    }
#undef ACCUM_EDGE
    __syncthreads();

    // ---- node finish: 4 threads per node (j = tid>>2 owns node, q = tid&3 owns 4 feats)
    int j = tid >> 2, q = tid & 3;
    int n = b * BUCK + j;
    if (n >= NN) return;
    float4 aq;
    const float* ar = &acc[j * 17 + q * 4];
    aq.x = ar[0]; aq.y = ar[1]; aq.z = ar[2]; aq.w = ar[3];
    // self loop (hs = h*dis, self coef dn*dn)
    uint2 sh = hs[(size_t)n * 4 + q];
    __half2* sp = reinterpret_cast<__half2*>(&sh);
    float2 s0 = __half22float2(sp[0]), s1 = __half22float2(sp[1]);
    float dn = dis[n];
    float4 b4 = ((const float4*)bias)[q];
    float4 z;
    z.x = fmaf(aq.x + s0.x, dn, b4.x);
    z.y = fmaf(aq.y + s0.y, dn, b4.y);
    z.z = fmaf(aq.z + s1.x, dn, b4.z);
    z.w = fmaf(aq.w + s1.y, dn, b4.w);
    if (RELU) {
        z.x = fmaxf(z.x, 0.f); z.y = fmaxf(z.y, 0.f);
        z.z = fmaxf(z.z, 0.f); z.w = fmaxf(z.w, 0.f);
    }
    if (FUSE_POOL) {
        float4 w4 = ((const float4*)Wn)[q];
        float s = z.x * w4.x + z.y * w4.y + z.z * w4.z + z.w * w4.w;
        s += __shfl_xor(s, 1);
        s += __shfl_xor(s, 2);
        if (q == 0) {
            int g = batch[n];
            unsafeAtomicAdd(&pool[g], s);
            atomicAdd(&gcnt[g], 1);
        }
    } else {
        // quad exchange + 16x16 transform (verified layout from round-0 kernel)
        float4 vals[4];
        vals[0] = z;
        vals[1] = shfl_xor4(z, 1);
        vals[2] = shfl_xor4(z, 2);
        vals[3] = shfl_xor4(z, 3);
        const float4* sW4 = (const float4*)sW;
        float4 hv = make_float4(0.f, 0.f, 0.f, 0.f);
#pragma unroll
        for (int mm = 0; mm < 4; mm++) {
            float4 v = vals[mm];
            int rb = (q ^ mm) << 2;
            float4 w;
            w = sW4[(rb + 0) * 4 + q];
            hv.x += v.x * w.x; hv.y += v.x * w.y; hv.z += v.x * w.z; hv.w += v.x * w.w;
            w = sW4[(rb + 1) * 4 + q];
            hv.x += v.y * w.x; hv.y += v.y * w.y; hv.z += v.y * w.z; hv.w += v.y * w.w;
            w = sW4[(rb + 2) * 4 + q];
            hv.x += v.z * w.x; hv.y += v.z * w.y; hv.z += v.z * w.z; hv.w += v.z * w.w;
            w = sW4[(rb + 3) * 4 + q];
            hv.x += v.w * w.x; hv.y += v.w * w.y; hv.z += v.w * w.z; hv.w += v.w * w.w;
        }
        hs_out[(size_t)n * 4 + q] = pack4(hv.x * dn, hv.y * dn, hv.z * dn, hv.w * dn);
    }
}

__global__ void finalize(const float* __restrict__ pool, const int* __restrict__ gcnt,
                         const float* __restrict__ bo, float* __restrict__ out) {
    int g = blockIdx.x * 256 + threadIdx.x;
    if (g < NG) {
        float c = fmaxf((float)gcnt[g], 1.0f);
        out[g] = pool[g] / c + bo[0];
    }
}

extern "C" void kernel_launch(void* const* d_in, const int* in_sizes, int n_in,
                              void* d_out, int out_size, void* d_ws, size_t ws_size,
                              hipStream_t stream) {
    const int*   types = (const int*)d_in[0];
    const int*   pos   = (const int*)d_in[1];
    const int*   ei    = (const int*)d_in[2];   // [2, E]: src then dst
    const int*   batch = (const int*)d_in[3];
    const float* W1  = (const float*)d_in[4];
    const float* b1  = (const float*)d_in[5];
    const float* W2  = (const float*)d_in[6];
    const float* b2  = (const float*)d_in[7];
    const float* Wg0 = (const float*)d_in[8];
    const float* bg0 = (const float*)d_in[9];
    const float* Wg1 = (const float*)d_in[10];
    const float* bg1 = (const float*)d_in[11];
    const float* Wg2 = (const float*)d_in[12];
    const float* bg2 = (const float*)d_in[13];
    const float* Wo  = (const float*)d_in[14];
    const float* bo  = (const float*)d_in[15];
    float* out = (float*)d_out;

    const int* esrc = ei;
    const int* edst = ei + NE;

    // ---- workspace layout (ints), all 16B-aligned ----
    int*   bcnt  = (int*)d_ws;                   // 2048 (zeroed)
    int*   bfill = bcnt + 2048;                  // 2048 (zeroed)
    float* pool  = (float*)(bfill + 2048);       // 1024 (zeroed)
    int*   gcnt  = (int*)(pool + NG);            // 1024 (zeroed)
    int*   bbase = gcnt + NG;                    // 2048
    float* dis   = (float*)(bbase + 2048);       // NP floats
    int*   part  = (int*)(dis + NP);             // NE  (persists across layers)
    uint2* hsA   = (uint2*)(part + NE);          // NP*4 uint2 = 3.2 MB
    uint2* hsB   = (uint2*)((int*)hsA + NP * 8); // 3.2 MB
    (void)ws_size; (void)n_in; (void)in_sizes; (void)out_size;

    hipMemsetAsync(d_ws, 0, (size_t)(4096 + 2 * NG) * sizeof(int), stream);

    const int NB256 = (NN + 255) / 256;          // 391

    hist_buckets<<<NBLK, 256, 0, stream>>>(edst, bcnt);
    scan_buckets<<<1, 256, 0, stream>>>(bcnt, bbase);
    partition<<<NBLK, 256, 0, stream>>>(esrc, edst, bbase, bfill, part);
    deg_dis<<<NBUCK, 256, 0, stream>>>(part, bbase, bcnt, dis);

    // layer 0 input: hs0 = (z0 @ Wg0) * dis  (fp16)
    embed_tf0<<<NB256, 256, 0, stream>>>(types, pos, W1, b1, W2, b2, Wg0, dis, hsA);

    // layer 0: agg + relu + transform Wg1 -> hsB
    agg_fused<1, 0><<<NBUCK, 256, 0, stream>>>(hsA, part, bbase, bcnt, dis, bg0, Wg1,
                                               hsB, batch, pool, gcnt);
    // layer 1: agg + relu + transform Wg2 -> hsA
    agg_fused<1, 0><<<NBUCK, 256, 0, stream>>>(hsB, part, bbase, bcnt, dis, bg1, Wg2,
                                               hsA, batch, pool, gcnt);
    // layer 2: agg (no relu) + Wo dot + pool
    agg_fused<0, 1><<<NBUCK, 256, 0, stream>>>(hsA, part, bbase, bcnt, dis, bg2, Wo,
                                               hsB /*unused*/, batch, pool, gcnt);

    finalize<<<(NG + 255) / 256, 256, 0, stream>>>(pool, gcnt, bo, out);
}

// Round 6
// 352.008 us; speedup vs baseline: 3.3160x; 3.1165x over previous
//
#include <hip/hip_runtime.h>
#include <hip/hip_fp16.h>

#define NN 100000
#define NE 3200000
#define NG 1024
#define NP 100352            // NN padded to multiple of 256
#define NBUCK 391            // ceil(NN/256) buckets of 256 dst nodes
#define NBLK 256
#define CHUNK ((NE + NBLK - 1) / NBLK)
#define WINCAP 12288

typedef int v4i __attribute__((ext_vector_type(4)));

// ---------- fp16 pack/unpack helpers ----------
static __device__ inline void acc_u2(float4& acc, uint2 u) {
    __half2* ph = reinterpret_cast<__half2*>(&u);
    float2 lo = __half22float2(ph[0]);
    float2 hi = __half22float2(ph[1]);
    acc.x += lo.x; acc.y += lo.y; acc.z += hi.x; acc.w += hi.y;
}
static __device__ inline uint2 pack4(float a, float b, float c, float d) {
    __half2 lo = __floats2half2_rn(a, b);
    __half2 hi = __floats2half2_rn(c, d);
    uint2 u;
    u.x = *reinterpret_cast<unsigned int*>(&lo);
    u.y = *reinterpret_cast<unsigned int*>(&hi);
    return u;
}
static __device__ inline float4 shfl_xor4(float4 v, int m) {
    float4 r;
    r.x = __shfl_xor(v.x, m); r.y = __shfl_xor(v.y, m);
    r.z = __shfl_xor(v.z, m); r.w = __shfl_xor(v.w, m);
    return r;
}

// ---- k1: per-bucket edge histogram ----
__global__ void hist_buckets(const int* __restrict__ dst, int* __restrict__ bcnt) {
    __shared__ int sm[NBUCK];
    int tid = threadIdx.x;
    for (int i = tid; i < NBUCK; i += 256) sm[i] = 0;
    __syncthreads();
    int s = blockIdx.x * CHUNK, e = min(NE, s + CHUNK);
    for (int i = s + tid; i < e; i += 256) atomicAdd(&sm[dst[i] >> 8], 1);
    __syncthreads();
    for (int i = tid; i < NBUCK; i += 256)
        if (sm[i]) atomicAdd(&bcnt[i], sm[i]);
}

// ---- k2: exclusive scan of bucket counts ----
__global__ void scan_buckets(const int* __restrict__ bcnt, int* __restrict__ bbase) {
    __shared__ int tmp[512];
    int tid = threadIdx.x;
    int v = (tid < NBUCK) ? bcnt[tid] : 0;
    tmp[tid] = v;
    __syncthreads();
    for (int off = 1; off < 512; off <<= 1) {
        int t = (tid >= off) ? tmp[tid - off] : 0;
        __syncthreads();
        tmp[tid] += t;
        __syncthreads();
    }
    if (tid < NBUCK) bbase[tid] = tmp[tid] - v;
}

// ---- k3: partition edges into bucket regions, packed (dst&255)<<17 | src ----
__global__ void partition(const int* __restrict__ src, const int* __restrict__ dst,
                          const int* __restrict__ bbase, int* __restrict__ bfill,
                          int* __restrict__ part) {
    __shared__ int smh[NBUCK];
    __shared__ int smc[NBUCK];
    int tid = threadIdx.x;
    for (int i = tid; i < NBUCK; i += 256) smh[i] = 0;
    __syncthreads();
    int s = blockIdx.x * CHUNK, e = min(NE, s + CHUNK);
    for (int i = s + tid; i < e; i += 256) atomicAdd(&smh[dst[i] >> 8], 1);
    __syncthreads();
    for (int i = tid; i < NBUCK; i += 256) {
        int c = smh[i];
        smc[i] = c ? (bbase[i] + atomicAdd(&bfill[i], c)) : 0;
    }
    __syncthreads();
    for (int i = s + tid; i < e; i += 256) {
        int d = dst[i];
        int b = d >> 8;
        int p = atomicAdd(&smc[b], 1);
        part[p] = src[i] | ((d & 255) << 17);
    }
}

// ---- k4: per-bucket CSR build in LDS; sequential write-out; also computes dis ----
__global__ void build_csr(const int* __restrict__ part, const int* __restrict__ bbase,
                          const int* __restrict__ bcnt, int* __restrict__ cnt,
                          int* __restrict__ offs, float* __restrict__ dis,
                          int* __restrict__ srcs) {
    __shared__ int sm_cnt[256];
    __shared__ int sm_off[256];
    __shared__ int sm_cur[256];
    __shared__ int sm_win[WINCAP];
    int b = blockIdx.x, tid = threadIdx.x;
    int base = bbase[b], m = bcnt[b];
    sm_cnt[tid] = 0;
    __syncthreads();
    for (int i = tid; i < m; i += 256) atomicAdd(&sm_cnt[part[base + i] >> 17], 1);
    __syncthreads();
    int v = sm_cnt[tid];
    sm_off[tid] = v;
    __syncthreads();
    for (int off = 1; off < 256; off <<= 1) {
        int t = (tid >= off) ? sm_off[tid - off] : 0;
        __syncthreads();
        sm_off[tid] += t;
        __syncthreads();
    }
    int excl = sm_off[tid] - v;
    int n = b * 256 + tid;
    if (n < NN) {
        cnt[n] = v;
        offs[n] = base + excl;
        dis[n] = rsqrtf((float)v + 1.0f);
    }
    sm_cur[tid] = excl;
    __syncthreads();
    if (m <= WINCAP) {
        for (int i = tid; i < m; i += 256) {
            int p = part[base + i];
            int l = atomicAdd(&sm_cur[p >> 17], 1);
            sm_win[l] = p & 0x1FFFF;
        }
        __syncthreads();
        for (int i = tid; i < m; i += 256) srcs[base + i] = sm_win[i];
    } else {
        for (int i = tid; i < m; i += 256) {
            int p = part[base + i];
            int l = atomicAdd(&sm_cur[p >> 17], 1);
            srcs[base + l] = p & 0x1FFFF;
        }
    }
}

// ---- embed one-hot + transform by Wg0, premultiply dis, fp16 out ----
__global__ void embed_tf0(const int* __restrict__ types, const int* __restrict__ pos,
                          const float* __restrict__ W1, const float* __restrict__ b1,
                          const float* __restrict__ W2, const float* __restrict__ b2,
                          const float* __restrict__ Wg0, const float* __restrict__ dis,
                          uint2* __restrict__ hs) {
    __shared__ float sW[32 * 16];
    int tid = threadIdx.x;
    sW[tid] = Wg0[tid];
    sW[tid + 256] = Wg0[tid + 256];
    __syncthreads();
    int n = blockIdx.x * 256 + tid;
    if (n >= NN) return;
    int ty = types[n], pp = pos[n];
    float z[32];
#pragma unroll
    for (int j = 0; j < 16; j++) z[j] = W1[ty * 16 + j] + b1[j];
#pragma unroll
    for (int j = 0; j < 16; j++) z[16 + j] = W2[pp * 16 + j] + b2[j];
    float dn = dis[n];
    uint2 o[4];
#pragma unroll
    for (int q = 0; q < 4; q++) {
        float hv[4];
#pragma unroll
        for (int m = 0; m < 4; m++) {
            float a = 0.0f;
#pragma unroll
            for (int k = 0; k < 32; k++) a += z[k] * sW[k * 16 + q * 4 + m];
            hv[m] = a * dn;
        }
        o[q] = pack4(hv[0], hv[1], hv[2], hv[3]);
    }
#pragma unroll
    for (int q = 0; q < 4; q++) hs[(size_t)n * 4 + q] = o[q];
}

// ---- fused aggregate + (transform | pool): 8 threads per node ----
// t = gid&7: q = t&3 owns 4 features, h = t>>2 owns half the edge list.
// Per-half chunk walk with branchless clamped srcs prefetch (min-index, no
// divergent guards -> round-1 failure mode avoided) and nontemporal srcs
// loads (protect hs L2 residency from the 12.8 MB srcs stream).
template <int RELU, int FUSE_POOL>
__global__ void agg_tf(const uint2* __restrict__ hs, const int* __restrict__ srcs,
                       const int* __restrict__ offs, const int* __restrict__ cnt,
                       const float* __restrict__ dis, const float* __restrict__ bias,
                       const float* __restrict__ Wn, uint2* __restrict__ hs_out,
                       const int* __restrict__ batch,
                       float* __restrict__ pool, int* __restrict__ gcnt) {
    __shared__ float sW[256];
    int tid = threadIdx.x;
    if (!FUSE_POOL) {
        sW[tid] = Wn[tid];
        __syncthreads();
    }
    int gid = blockIdx.x * 256 + tid;
    int n = gid >> 3, t = gid & 7;
    int q = t & 3, h = t >> 2;
    if (n >= NN) return;
    int beg = offs[n], deg = cnt[n];
    float dn = dis[n];
    const uint2* __restrict__ hq = hs + q;
    float4 acc = make_float4(0.f, 0.f, 0.f, 0.f);

    // scalar peel to 16B alignment (h==0 does it; <=3 edges)
    int mis = (4 - (beg & 3)) & 3;
    int pre = min(mis, deg);
    if (h == 0) {
        for (int i = 0; i < pre; i++) {
            int s = srcs[beg + i];
            acc_u2(acc, hq[(size_t)s * 4]);
        }
    }
    int rem = deg - pre;
    int nch = rem >> 2;           // aligned 4-edge chunks
    int abase = beg + pre;
    const v4i* sp = (const v4i*)(srcs + abase);
    int nch0 = nch >> 1;
    int c0 = h ? nch0 : 0;
    int c1 = h ? nch : nch0;
    if (c0 < c1) {
        v4i s = __builtin_nontemporal_load(sp + c0);
        for (int c = c0; c < c1; c++) {
            v4i sN = __builtin_nontemporal_load(sp + min(c + 1, c1 - 1));
            uint2 g0 = hq[(size_t)s.x * 4];
            uint2 g1 = hq[(size_t)s.y * 4];
            uint2 g2 = hq[(size_t)s.z * 4];
            uint2 g3 = hq[(size_t)s.w * 4];
            acc_u2(acc, g0); acc_u2(acc, g1); acc_u2(acc, g2); acc_u2(acc, g3);
            s = sN;
        }
    }
    // scalar tail (h==1 does it; <=3 edges)
    if (h == 1) {
        for (int i = abase + nch * 4; i < beg + deg; i++) {
            int s = srcs[i];
            acc_u2(acc, hq[(size_t)s * 4]);
        }
    }

    // fold the two halves: lanes t and t^4 hold the same node
    float4 o4 = shfl_xor4(acc, 4);
    acc.x += o4.x; acc.y += o4.y; acc.z += o4.z; acc.w += o4.w;

    acc_u2(acc, hq[(size_t)n * 4]);   // self loop (hs = h*dis, self coef dn*dn)
    float4 b4 = ((const float4*)bias)[q];
    acc.x = fmaf(acc.x, dn, b4.x);
    acc.y = fmaf(acc.y, dn, b4.y);
    acc.z = fmaf(acc.z, dn, b4.z);
    acc.w = fmaf(acc.w, dn, b4.w);
    if (RELU) {
        acc.x = fmaxf(acc.x, 0.f); acc.y = fmaxf(acc.y, 0.f);
        acc.z = fmaxf(acc.z, 0.f); acc.w = fmaxf(acc.w, 0.f);
    }
    if (FUSE_POOL) {
        float4 w4 = ((const float4*)Wn)[q];
        float s = acc.x * w4.x + acc.y * w4.y + acc.z * w4.z + acc.w * w4.w;
        s += __shfl_xor(s, 1);
        s += __shfl_xor(s, 2);
        if (t == 0) {
            int g = batch[n];
            atomicAdd(&pool[g], s);
            atomicAdd(&gcnt[g], 1);
        }
    } else {
        // exchange quad features, compute z @ Wn for this thread's 4 outputs
        // (masks 1,2,3 stay within the q nibble; both halves compute identical
        // values post-fold, only h==0 stores)
        float4 vals[4];
        vals[0] = acc;
        vals[1] = shfl_xor4(acc, 1);
        vals[2] = shfl_xor4(acc, 2);
        vals[3] = shfl_xor4(acc, 3);
        const float4* sW4 = (const float4*)sW;
        float4 hv = make_float4(0.f, 0.f, 0.f, 0.f);
#pragma unroll
        for (int m = 0; m < 4; m++) {
            float4 v = vals[m];
            int rb = (q ^ m) << 2;
            float4 w;
            w = sW4[(rb + 0) * 4 + q];
            hv.x += v.x * w.x; hv.y += v.x * w.y; hv.z += v.x * w.z; hv.w += v.x * w.w;
            w = sW4[(rb + 1) * 4 + q];
            hv.x += v.y * w.x; hv.y += v.y * w.y; hv.z += v.y * w.z; hv.w += v.y * w.w;
            w = sW4[(rb + 2) * 4 + q];
            hv.x += v.z * w.x; hv.y += v.z * w.y; hv.z += v.z * w.z; hv.w += v.z * w.w;
            w = sW4[(rb + 3) * 4 + q];
            hv.x += v.w * w.x; hv.y += v.w * w.y; hv.z += v.w * w.z; hv.w += v.w * w.w;
        }
        if (h == 0)
            hs_out[(size_t)n * 4 + q] = pack4(hv.x * dn, hv.y * dn, hv.z * dn, hv.w * dn);
    }
}

__global__ void finalize(const float* __restrict__ pool, const int* __restrict__ gcnt,
                         const float* __restrict__ bo, float* __restrict__ out) {
    int g = blockIdx.x * 256 + threadIdx.x;
    if (g < NG) {
        float c = fmaxf((float)gcnt[g], 1.0f);
        out[g] = pool[g] / c + bo[0];
    }
}

extern "C" void kernel_launch(void* const* d_in, const int* in_sizes, int n_in,
                              void* d_out, int out_size, void* d_ws, size_t ws_size,
                              hipStream_t stream) {
    const int*   types = (const int*)d_in[0];
    const int*   pos   = (const int*)d_in[1];
    const int*   ei    = (const int*)d_in[2];   // [2, E]: src then dst
    const int*   batch = (const int*)d_in[3];
    const float* W1  = (const float*)d_in[4];
    const float* b1  = (const float*)d_in[5];
    const float* W2  = (const float*)d_in[6];
    const float* b2  = (const float*)d_in[7];
    const float* Wg0 = (const float*)d_in[8];
    const float* bg0 = (const float*)d_in[9];
    const float* Wg1 = (const float*)d_in[10];
    const float* bg1 = (const float*)d_in[11];
    const float* Wg2 = (const float*)d_in[12];
    const float* bg2 = (const float*)d_in[13];
    const float* Wo  = (const float*)d_in[14];
    const float* bo  = (const float*)d_in[15];
    float* out = (float*)d_out;

    const int* esrc = ei;
    const int* edst = ei + NE;

    // ---- workspace layout (ints) ----
    int*   bcnt  = (int*)d_ws;                   // 512  (zeroed)
    int*   bfill = bcnt + 512;                   // 512  (zeroed)
    float* pool  = (float*)(bfill + 512);        // 1024 (zeroed)
    int*   gcnt  = (int*)(pool + NG);            // 1024 (zeroed)
    int*   bbase = gcnt + NG;                    // 512
    int*   cnt   = bbase + 512;                  // NP
    int*   offs  = cnt + NP;                     // NP
    float* dis   = (float*)(offs + NP);          // NP
    int*   srcs  = (int*)(dis + NP);             // NE  (16B-aligned: offset 304640 ints)
    int*   part  = srcs + NE;                    // NE  (hs buffers alias this)
    uint2* hsA   = (uint2*)part;                 // NP*4 uint2 = 3.2 MB
    uint2* hsB   = (uint2*)(part + NE / 2);      // 3.2 MB (part is 12.8 MB)
    (void)ws_size; (void)n_in; (void)in_sizes; (void)out_size;

    hipMemsetAsync(d_ws, 0, (size_t)(1024 + 2 * NG) * sizeof(int), stream);

    const int NB256 = (NN + 255) / 256;          // 391
    const int QB8 = (NN * 8 + 255) / 256;        // 3125

    hist_buckets<<<NBLK, 256, 0, stream>>>(edst, bcnt);
    scan_buckets<<<1, 512, 0, stream>>>(bcnt, bbase);
    partition<<<NBLK, 256, 0, stream>>>(esrc, edst, bbase, bfill, part);
    build_csr<<<NBUCK, 256, 0, stream>>>(part, bbase, bcnt, cnt, offs, dis, srcs);

    // layer 0 input: hs0 = (z0 @ Wg0) * dis  (fp16)
    embed_tf0<<<NB256, 256, 0, stream>>>(types, pos, W1, b1, W2, b2, Wg0, dis, hsA);
    // layer 0 agg + relu + transform Wg1 -> hs1
    agg_tf<1, 0><<<QB8, 256, 0, stream>>>(hsA, srcs, offs, cnt, dis, bg0, Wg1, hsB,
                                          batch, pool, gcnt);
    // layer 1 agg + relu + transform Wg2 -> hs2
    agg_tf<1, 0><<<QB8, 256, 0, stream>>>(hsB, srcs, offs, cnt, dis, bg1, Wg2, hsA,
                                          batch, pool, gcnt);
    // layer 2 agg (no relu) + Wo dot + pool
    agg_tf<0, 1><<<QB8, 256, 0, stream>>>(hsA, srcs, offs, cnt, dis, bg2, Wo, hsB /*unused*/,
                                          batch, pool, gcnt);

    finalize<<<(NG + 255) / 256, 256, 0, stream>>>(pool, gcnt, bo, out);
}

// Round 8
// 342.203 us; speedup vs baseline: 3.4110x; 1.0287x over previous
//
#include <hip/hip_runtime.h>
#include <hip/hip_fp16.h>

#define NN 100000
#define NE 3200000
#define NG 1024
#define NP 100352            // NN padded to multiple of 256
#define NBUCK 391            // ceil(NN/256) buckets of 256 dst nodes
#define NBLK 256
#define CHUNK ((NE + NBLK - 1) / NBLK)
#define WINCAP 12288

typedef int v4i __attribute__((ext_vector_type(4)));

// ---------- fp16 pack/unpack helpers ----------
static __device__ inline void acc_u4(float4& a, float4& b, uint4 u) {
    __half2* ph = reinterpret_cast<__half2*>(&u);
    float2 f0 = __half22float2(ph[0]);
    float2 f1 = __half22float2(ph[1]);
    float2 f2 = __half22float2(ph[2]);
    float2 f3 = __half22float2(ph[3]);
    a.x += f0.x; a.y += f0.y; a.z += f1.x; a.w += f1.y;
    b.x += f2.x; b.y += f2.y; b.z += f3.x; b.w += f3.y;
}
static __device__ inline uint2 pack4(float a, float b, float c, float d) {
    __half2 lo = __floats2half2_rn(a, b);
    __half2 hi = __floats2half2_rn(c, d);
    uint2 u;
    u.x = *reinterpret_cast<unsigned int*>(&lo);
    u.y = *reinterpret_cast<unsigned int*>(&hi);
    return u;
}
static __device__ inline float4 shfl_xor4(float4 v, int m) {
    float4 r;
    r.x = __shfl_xor(v.x, m); r.y = __shfl_xor(v.y, m);
    r.z = __shfl_xor(v.z, m); r.w = __shfl_xor(v.w, m);
    return r;
}

// ---- k1: per-bucket edge histogram ----
__global__ void hist_buckets(const int* __restrict__ dst, int* __restrict__ bcnt) {
    __shared__ int sm[NBUCK];
    int tid = threadIdx.x;
    for (int i = tid; i < NBUCK; i += 256) sm[i] = 0;
    __syncthreads();
    int s = blockIdx.x * CHUNK, e = min(NE, s + CHUNK);
    for (int i = s + tid; i < e; i += 256) atomicAdd(&sm[dst[i] >> 8], 1);
    __syncthreads();
    for (int i = tid; i < NBUCK; i += 256)
        if (sm[i]) atomicAdd(&bcnt[i], sm[i]);
}

// ---- k2: exclusive scan of bucket counts ----
__global__ void scan_buckets(const int* __restrict__ bcnt, int* __restrict__ bbase) {
    __shared__ int tmp[512];
    int tid = threadIdx.x;
    int v = (tid < NBUCK) ? bcnt[tid] : 0;
    tmp[tid] = v;
    __syncthreads();
    for (int off = 1; off < 512; off <<= 1) {
        int t = (tid >= off) ? tmp[tid - off] : 0;
        __syncthreads();
        tmp[tid] += t;
        __syncthreads();
    }
    if (tid < NBUCK) bbase[tid] = tmp[tid] - v;
}

// ---- k3: partition edges into bucket regions, packed (dst&255)<<17 | src ----
__global__ void partition(const int* __restrict__ src, const int* __restrict__ dst,
                          const int* __restrict__ bbase, int* __restrict__ bfill,
                          int* __restrict__ part) {
    __shared__ int smh[NBUCK];
    __shared__ int smc[NBUCK];
    int tid = threadIdx.x;
    for (int i = tid; i < NBUCK; i += 256) smh[i] = 0;
    __syncthreads();
    int s = blockIdx.x * CHUNK, e = min(NE, s + CHUNK);
    for (int i = s + tid; i < e; i += 256) atomicAdd(&smh[dst[i] >> 8], 1);
    __syncthreads();
    for (int i = tid; i < NBUCK; i += 256) {
        int c = smh[i];
        smc[i] = c ? (bbase[i] + atomicAdd(&bfill[i], c)) : 0;
    }
    __syncthreads();
    for (int i = s + tid; i < e; i += 256) {
        int d = dst[i];
        int b = d >> 8;
        int p = atomicAdd(&smc[b], 1);
        part[p] = src[i] | ((d & 255) << 17);
    }
}

// ---- k4: per-bucket CSR build in LDS; sequential write-out; also computes dis ----
__global__ void build_csr(const int* __restrict__ part, const int* __restrict__ bbase,
                          const int* __restrict__ bcnt, int* __restrict__ cnt,
                          int* __restrict__ offs, float* __restrict__ dis,
                          int* __restrict__ srcs) {
    __shared__ int sm_cnt[256];
    __shared__ int sm_off[256];
    __shared__ int sm_cur[256];
    __shared__ int sm_win[WINCAP];
    int b = blockIdx.x, tid = threadIdx.x;
    int base = bbase[b], m = bcnt[b];
    sm_cnt[tid] = 0;
    __syncthreads();
    for (int i = tid; i < m; i += 256) atomicAdd(&sm_cnt[part[base + i] >> 17], 1);
    __syncthreads();
    int v = sm_cnt[tid];
    sm_off[tid] = v;
    __syncthreads();
    for (int off = 1; off < 256; off <<= 1) {
        int t = (tid >= off) ? sm_off[tid - off] : 0;
        __syncthreads();
        sm_off[tid] += t;
        __syncthreads();
    }
    int excl = sm_off[tid] - v;
    int n = b * 256 + tid;
    if (n < NN) {
        cnt[n] = v;
        offs[n] = base + excl;
        dis[n] = rsqrtf((float)v + 1.0f);
    }
    sm_cur[tid] = excl;
    __syncthreads();
    if (m <= WINCAP) {
        for (int i = tid; i < m; i += 256) {
            int p = part[base + i];
            int l = atomicAdd(&sm_cur[p >> 17], 1);
            sm_win[l] = p & 0x1FFFF;
        }
        __syncthreads();
        for (int i = tid; i < m; i += 256) srcs[base + i] = sm_win[i];
    } else {
        for (int i = tid; i < m; i += 256) {
            int p = part[base + i];
            int l = atomicAdd(&sm_cur[p >> 17], 1);
            srcs[base + l] = p & 0x1FFFF;
        }
    }
}

// ---- embed one-hot + transform by Wg0, premultiply dis, fp16 out ----
__global__ void embed_tf0(const int* __restrict__ types, const int* __restrict__ pos,
                          const float* __restrict__ W1, const float* __restrict__ b1,
                          const float* __restrict__ W2, const float* __restrict__ b2,
                          const float* __restrict__ Wg0, const float* __restrict__ dis,
                          uint2* __restrict__ hs) {
    __shared__ float sW[32 * 16];
    int tid = threadIdx.x;
    sW[tid] = Wg0[tid];
    sW[tid + 256] = Wg0[tid + 256];
    __syncthreads();
    int n = blockIdx.x * 256 + tid;
    if (n >= NN) return;
    int ty = types[n], pp = pos[n];
    float z[32];
#pragma unroll
    for (int j = 0; j < 16; j++) z[j] = W1[ty * 16 + j] + b1[j];
#pragma unroll
    for (int j = 0; j < 16; j++) z[16 + j] = W2[pp * 16 + j] + b2[j];
    float dn = dis[n];
    uint2 o[4];
#pragma unroll
    for (int q = 0; q < 4; q++) {
        float hv[4];
#pragma unroll
        for (int m = 0; m < 4; m++) {
            float a = 0.0f;
#pragma unroll
            for (int k = 0; k < 32; k++) a += z[k] * sW[k * 16 + q * 4 + m];
            hv[m] = a * dn;
        }
        o[q] = pack4(hv[0], hv[1], hv[2], hv[3]);
    }
#pragma unroll
    for (int q = 0; q < 4; q++) hs[(size_t)n * 4 + q] = o[q];
}

// ---- fused aggregate + (transform | pool): 4 threads per node ----
// t = gid&3: q = t&1 owns 8 features (ONE uint4 = 16B gather per edge),
//            h = t>>1 owns half the edge list.
// 2 requests/edge instead of 4 (round-6 post-mortem: per-CU random-request
// ceiling ~0.25 req/cy is the wall; requests, not bytes, are the cost unit).
// FUSE_POOL reduce: AFTER the h-fold (mask 2), only the mask-1 exchange
// remains (round-7 bug: keeping the mask-2 step double-counted the pool).
template <int RELU, int FUSE_POOL>
__global__ void agg_tf(const uint2* __restrict__ hs, const int* __restrict__ srcs,
                       const int* __restrict__ offs, const int* __restrict__ cnt,
                       const float* __restrict__ dis, const float* __restrict__ bias,
                       const float* __restrict__ Wn, uint2* __restrict__ hs_out,
                       const int* __restrict__ batch,
                       float* __restrict__ pool, int* __restrict__ gcnt) {
    __shared__ float sW[256];
    int tid = threadIdx.x;
    if (!FUSE_POOL) {
        sW[tid] = Wn[tid];
        __syncthreads();
    }
    int gid = blockIdx.x * 256 + tid;
    int n = gid >> 2, t = gid & 3;
    int q = t & 1, h = t >> 1;
    if (n >= NN) return;
    int beg = offs[n], deg = cnt[n];
    float dn = dis[n];
    const uint4* __restrict__ hq = (const uint4*)hs + q;   // hq[2*src] = 16B half-row
    float4 acc0 = make_float4(0.f, 0.f, 0.f, 0.f);
    float4 acc1 = make_float4(0.f, 0.f, 0.f, 0.f);

    // scalar peel to 16B alignment of srcs (h==0 does it; <=3 edges)
    int mis = (4 - (beg & 3)) & 3;
    int pre = min(mis, deg);
    if (h == 0) {
        for (int i = 0; i < pre; i++) {
            int s = srcs[beg + i];
            acc_u4(acc0, acc1, hq[(size_t)s * 2]);
        }
    }
    int rem = deg - pre;
    int nch = rem >> 2;           // aligned 4-edge chunks
    int abase = beg + pre;
    const v4i* sp = (const v4i*)(srcs + abase);
    int nch0 = nch >> 1;
    int c0 = h ? nch0 : 0;
    int c1 = h ? nch : nch0;
    if (c0 < c1) {
        v4i s = __builtin_nontemporal_load(sp + c0);
        for (int c = c0; c < c1; c++) {
            v4i sN = __builtin_nontemporal_load(sp + min(c + 1, c1 - 1));
            uint4 g0 = hq[(size_t)s.x * 2];
            uint4 g1 = hq[(size_t)s.y * 2];
            uint4 g2 = hq[(size_t)s.z * 2];
            uint4 g3 = hq[(size_t)s.w * 2];
            acc_u4(acc0, acc1, g0);
            acc_u4(acc0, acc1, g1);
            acc_u4(acc0, acc1, g2);
            acc_u4(acc0, acc1, g3);
            s = sN;
        }
    }
    // scalar tail (h==1 does it; <=3 edges)
    if (h == 1) {
        for (int i = abase + nch * 4; i < beg + deg; i++) {
            int s = srcs[i];
            acc_u4(acc0, acc1, hq[(size_t)s * 2]);
        }
    }

    // fold the two edge-halves: lanes t and t^2 hold the same (node, q)
    float4 f0 = shfl_xor4(acc0, 2);
    float4 f1 = shfl_xor4(acc1, 2);
    acc0.x += f0.x; acc0.y += f0.y; acc0.z += f0.z; acc0.w += f0.w;
    acc1.x += f1.x; acc1.y += f1.y; acc1.z += f1.z; acc1.w += f1.w;

    // self loop (hs = h*dis, self coef dn*dn)
    acc_u4(acc0, acc1, hq[(size_t)n * 2]);

    float4 b0 = ((const float4*)bias)[q * 2];
    float4 b1 = ((const float4*)bias)[q * 2 + 1];
    acc0.x = fmaf(acc0.x, dn, b0.x); acc0.y = fmaf(acc0.y, dn, b0.y);
    acc0.z = fmaf(acc0.z, dn, b0.z); acc0.w = fmaf(acc0.w, dn, b0.w);
    acc1.x = fmaf(acc1.x, dn, b1.x); acc1.y = fmaf(acc1.y, dn, b1.y);
    acc1.z = fmaf(acc1.z, dn, b1.z); acc1.w = fmaf(acc1.w, dn, b1.w);
    if (RELU) {
        acc0.x = fmaxf(acc0.x, 0.f); acc0.y = fmaxf(acc0.y, 0.f);
        acc0.z = fmaxf(acc0.z, 0.f); acc0.w = fmaxf(acc0.w, 0.f);
        acc1.x = fmaxf(acc1.x, 0.f); acc1.y = fmaxf(acc1.y, 0.f);
        acc1.z = fmaxf(acc1.z, 0.f); acc1.w = fmaxf(acc1.w, 0.f);
    }
    if (FUSE_POOL) {
        float4 w0 = ((const float4*)Wn)[q * 2];
        float4 w1 = ((const float4*)Wn)[q * 2 + 1];
        float s = acc0.x * w0.x + acc0.y * w0.y + acc0.z * w0.z + acc0.w * w0.w
                + acc1.x * w1.x + acc1.y * w1.y + acc1.z * w1.z + acc1.w * w1.w;
        s += __shfl_xor(s, 1);     // sum the two q-halves; h already folded
        if (t == 0) {
            int g = batch[n];
            atomicAdd(&pool[g], s);
            atomicAdd(&gcnt[g], 1);
        }
    } else {
        // exchange 8-feature halves with partner lane (t^1, other q, same h);
        // post-fold both h copies are identical, only h==0 stores.
        float4 o0 = shfl_xor4(acc0, 1);
        float4 o1 = shfl_xor4(acc1, 1);
        float4 A0 = q ? o0 : acc0;   // feats 0-3
        float4 A1 = q ? o1 : acc1;   // feats 4-7
        float4 B0 = q ? acc0 : o0;   // feats 8-11
        float4 B1 = q ? acc1 : o1;   // feats 12-15
        float zf[16] = {A0.x, A0.y, A0.z, A0.w, A1.x, A1.y, A1.z, A1.w,
                        B0.x, B0.y, B0.z, B0.w, B1.x, B1.y, B1.z, B1.w};
        // outputs q*8 .. q*8+7:  hv[m] = sum_k zf[k] * Wn[k][q*8+m]
        const float4* sW4 = (const float4*)sW;
        float4 hva = make_float4(0.f, 0.f, 0.f, 0.f);
        float4 hvb = make_float4(0.f, 0.f, 0.f, 0.f);
#pragma unroll
        for (int k = 0; k < 16; k++) {
            float zk = zf[k];
            float4 wa = sW4[k * 4 + q * 2];
            float4 wb = sW4[k * 4 + q * 2 + 1];
            hva.x += zk * wa.x; hva.y += zk * wa.y;
            hva.z += zk * wa.z; hva.w += zk * wa.w;
            hvb.x += zk * wb.x; hvb.y += zk * wb.y;
            hvb.z += zk * wb.z; hvb.w += zk * wb.w;
        }
        if (h == 0) {
            uint2 lo = pack4(hva.x * dn, hva.y * dn, hva.z * dn, hva.w * dn);
            uint2 hi = pack4(hvb.x * dn, hvb.y * dn, hvb.z * dn, hvb.w * dn);
            uint4 o;
            o.x = lo.x; o.y = lo.y; o.z = hi.x; o.w = hi.y;
            ((uint4*)hs_out)[(size_t)n * 2 + q] = o;
        }
    }
}

__global__ void finalize(const float* __restrict__ pool, const int* __restrict__ gcnt,
                         const float* __restrict__ bo, float* __restrict__ out) {
    int g = blockIdx.x * 256 + threadIdx.x;
    if (g < NG) {
        float c = fmaxf((float)gcnt[g], 1.0f);
        out[g] = pool[g] / c + bo[0];
    }
}

extern "C" void kernel_launch(void* const* d_in, const int* in_sizes, int n_in,
                              void* d_out, int out_size, void* d_ws, size_t ws_size,
                              hipStream_t stream) {
    const int*   types = (const int*)d_in[0];
    const int*   pos   = (const int*)d_in[1];
    const int*   ei    = (const int*)d_in[2];   // [2, E]: src then dst
    const int*   batch = (const int*)d_in[3];
    const float* W1  = (const float*)d_in[4];
    const float* b1  = (const float*)d_in[5];
    const float* W2  = (const float*)d_in[6];
    const float* b2  = (const float*)d_in[7];
    const float* Wg0 = (const float*)d_in[8];
    const float* bg0 = (const float*)d_in[9];
    const float* Wg1 = (const float*)d_in[10];
    const float* bg1 = (const float*)d_in[11];
    const float* Wg2 = (const float*)d_in[12];
    const float* bg2 = (const float*)d_in[13];
    const float* Wo  = (const float*)d_in[14];
    const float* bo  = (const float*)d_in[15];
    float* out = (float*)d_out;

    const int* esrc = ei;
    const int* edst = ei + NE;

    // ---- workspace layout (ints) ----
    int*   bcnt  = (int*)d_ws;                   // 512  (zeroed)
    int*   bfill = bcnt + 512;                   // 512  (zeroed)
    float* pool  = (float*)(bfill + 512);        // 1024 (zeroed)
    int*   gcnt  = (int*)(pool + NG);            // 1024 (zeroed)
    int*   bbase = gcnt + NG;                    // 512
    int*   cnt   = bbase + 512;                  // NP
    int*   offs  = cnt + NP;                     // NP
    float* dis   = (float*)(offs + NP);          // NP
    int*   srcs  = (int*)(dis + NP);             // NE  (16B-aligned: offset 304640 ints)
    int*   part  = srcs + NE;                    // NE  (hs buffers alias this)
    uint2* hsA   = (uint2*)part;                 // NP*4 uint2 = 3.2 MB
    uint2* hsB   = (uint2*)(part + NE / 2);      // 3.2 MB (part is 12.8 MB)
    (void)ws_size; (void)n_in; (void)in_sizes; (void)out_size;

    hipMemsetAsync(d_ws, 0, (size_t)(1024 + 2 * NG) * sizeof(int), stream);

    const int NB256 = (NN + 255) / 256;          // 391
    const int QB4 = (NN * 4 + 255) / 256;        // 1563

    hist_buckets<<<NBLK, 256, 0, stream>>>(edst, bcnt);
    scan_buckets<<<1, 512, 0, stream>>>(bcnt, bbase);
    partition<<<NBLK, 256, 0, stream>>>(esrc, edst, bbase, bfill, part);
    build_csr<<<NBUCK, 256, 0, stream>>>(part, bbase, bcnt, cnt, offs, dis, srcs);

    // layer 0 input: hs0 = (z0 @ Wg0) * dis  (fp16)
    embed_tf0<<<NB256, 256, 0, stream>>>(types, pos, W1, b1, W2, b2, Wg0, dis, hsA);
    // layer 0 agg + relu + transform Wg1 -> hs1
    agg_tf<1, 0><<<QB4, 256, 0, stream>>>(hsA, srcs, offs, cnt, dis, bg0, Wg1, hsB,
                                          batch, pool, gcnt);
    // layer 1 agg + relu + transform Wg2 -> hs2
    agg_tf<1, 0><<<QB4, 256, 0, stream>>>(hsB, srcs, offs, cnt, dis, bg1, Wg2, hsA,
                                          batch, pool, gcnt);
    // layer 2 agg (no relu) + Wo dot + pool
    agg_tf<0, 1><<<QB4, 256, 0, stream>>>(hsA, srcs, offs, cnt, dis, bg2, Wo, hsB /*unused*/,
                                          batch, pool, gcnt);

    finalize<<<(NG + 255) / 256, 256, 0, stream>>>(pool, gcnt, bo, out);
}

// Round 9
// 331.888 us; speedup vs baseline: 3.5170x; 1.0311x over previous
//
#include <hip/hip_runtime.h>
#include <hip/hip_fp16.h>

#define NN 100000
#define NE 3200000
#define NG 1024
#define NP 100352            // NN padded to multiple of 256
#define NBUCK 391            // ceil(NN/256) buckets of 256 dst nodes
#define NBLK 256
#define CHUNK ((NE + NBLK - 1) / NBLK)
#define WINCAP 12288

// ---------- fp16 pack/unpack helpers ----------
static __device__ inline void acc_u2(float4& acc, uint2 u) {
    __half2* ph = reinterpret_cast<__half2*>(&u);
    float2 lo = __half22float2(ph[0]);
    float2 hi = __half22float2(ph[1]);
    acc.x += lo.x; acc.y += lo.y; acc.z += hi.x; acc.w += hi.y;
}
// L1-bypass 8B load (agent scope -> sc0/glc): no L1 MSHR entry, lands in
// the deep per-XCD L2 queues. Round-8 post-mortem: all gather variants hit
// ~16 cy per unique line per CU = per-CU L1 miss-queue cap (~12-24 lines in
// flight); L1 hit rate on the 3.2MB random table is ~1%, so bypass is free.
static __device__ inline uint2 ld_bypass(const uint2* p) {
    unsigned long long v = __hip_atomic_load(
        (const unsigned long long*)p, __ATOMIC_RELAXED, __HIP_MEMORY_SCOPE_AGENT);
    uint2 r;
    r.x = (unsigned int)v;
    r.y = (unsigned int)(v >> 32);
    return r;
}
static __device__ inline uint2 pack4(float a, float b, float c, float d) {
    __half2 lo = __floats2half2_rn(a, b);
    __half2 hi = __floats2half2_rn(c, d);
    uint2 u;
    u.x = *reinterpret_cast<unsigned int*>(&lo);
    u.y = *reinterpret_cast<unsigned int*>(&hi);
    return u;
}
static __device__ inline float4 shfl_xor4(float4 v, int m) {
    float4 r;
    r.x = __shfl_xor(v.x, m); r.y = __shfl_xor(v.y, m);
    r.z = __shfl_xor(v.z, m); r.w = __shfl_xor(v.w, m);
    return r;
}

// ---- k1: per-bucket edge histogram ----
__global__ void hist_buckets(const int* __restrict__ dst, int* __restrict__ bcnt) {
    __shared__ int sm[NBUCK];
    int tid = threadIdx.x;
    for (int i = tid; i < NBUCK; i += 256) sm[i] = 0;
    __syncthreads();
    int s = blockIdx.x * CHUNK, e = min(NE, s + CHUNK);
    for (int i = s + tid; i < e; i += 256) atomicAdd(&sm[dst[i] >> 8], 1);
    __syncthreads();
    for (int i = tid; i < NBUCK; i += 256)
        if (sm[i]) atomicAdd(&bcnt[i], sm[i]);
}

// ---- k2: exclusive scan of bucket counts ----
__global__ void scan_buckets(const int* __restrict__ bcnt, int* __restrict__ bbase) {
    __shared__ int tmp[512];
    int tid = threadIdx.x;
    int v = (tid < NBUCK) ? bcnt[tid] : 0;
    tmp[tid] = v;
    __syncthreads();
    for (int off = 1; off < 512; off <<= 1) {
        int t = (tid >= off) ? tmp[tid - off] : 0;
        __syncthreads();
        tmp[tid] += t;
        __syncthreads();
    }
    if (tid < NBUCK) bbase[tid] = tmp[tid] - v;
}

// ---- k3: partition edges into bucket regions, packed (dst&255)<<17 | src ----
__global__ void partition(const int* __restrict__ src, const int* __restrict__ dst,
                          const int* __restrict__ bbase, int* __restrict__ bfill,
                          int* __restrict__ part) {
    __shared__ int smh[NBUCK];
    __shared__ int smc[NBUCK];
    int tid = threadIdx.x;
    for (int i = tid; i < NBUCK; i += 256) smh[i] = 0;
    __syncthreads();
    int s = blockIdx.x * CHUNK, e = min(NE, s + CHUNK);
    for (int i = s + tid; i < e; i += 256) atomicAdd(&smh[dst[i] >> 8], 1);
    __syncthreads();
    for (int i = tid; i < NBUCK; i += 256) {
        int c = smh[i];
        smc[i] = c ? (bbase[i] + atomicAdd(&bfill[i], c)) : 0;
    }
    __syncthreads();
    for (int i = s + tid; i < e; i += 256) {
        int d = dst[i];
        int b = d >> 8;
        int p = atomicAdd(&smc[b], 1);
        part[p] = src[i] | ((d & 255) << 17);
    }
}

// ---- k4: per-bucket CSR build in LDS; sequential write-out; also computes dis ----
__global__ void build_csr(const int* __restrict__ part, const int* __restrict__ bbase,
                          const int* __restrict__ bcnt, int* __restrict__ cnt,
                          int* __restrict__ offs, float* __restrict__ dis,
                          int* __restrict__ srcs) {
    __shared__ int sm_cnt[256];
    __shared__ int sm_off[256];
    __shared__ int sm_cur[256];
    __shared__ int sm_win[WINCAP];
    int b = blockIdx.x, tid = threadIdx.x;
    int base = bbase[b], m = bcnt[b];
    sm_cnt[tid] = 0;
    __syncthreads();
    for (int i = tid; i < m; i += 256) atomicAdd(&sm_cnt[part[base + i] >> 17], 1);
    __syncthreads();
    int v = sm_cnt[tid];
    sm_off[tid] = v;
    __syncthreads();
    for (int off = 1; off < 256; off <<= 1) {
        int t = (tid >= off) ? sm_off[tid - off] : 0;
        __syncthreads();
        sm_off[tid] += t;
        __syncthreads();
    }
    int excl = sm_off[tid] - v;
    int n = b * 256 + tid;
    if (n < NN) {
        cnt[n] = v;
        offs[n] = base + excl;
        dis[n] = rsqrtf((float)v + 1.0f);
    }
    sm_cur[tid] = excl;
    __syncthreads();
    if (m <= WINCAP) {
        for (int i = tid; i < m; i += 256) {
            int p = part[base + i];
            int l = atomicAdd(&sm_cur[p >> 17], 1);
            sm_win[l] = p & 0x1FFFF;
        }
        __syncthreads();
        for (int i = tid; i < m; i += 256) srcs[base + i] = sm_win[i];
    } else {
        for (int i = tid; i < m; i += 256) {
            int p = part[base + i];
            int l = atomicAdd(&sm_cur[p >> 17], 1);
            srcs[base + l] = p & 0x1FFFF;
        }
    }
}

// ---- embed one-hot + transform by Wg0, premultiply dis, fp16 out ----
__global__ void embed_tf0(const int* __restrict__ types, const int* __restrict__ pos,
                          const float* __restrict__ W1, const float* __restrict__ b1,
                          const float* __restrict__ W2, const float* __restrict__ b2,
                          const float* __restrict__ Wg0, const float* __restrict__ dis,
                          uint2* __restrict__ hs) {
    __shared__ float sW[32 * 16];
    int tid = threadIdx.x;
    sW[tid] = Wg0[tid];
    sW[tid + 256] = Wg0[tid + 256];
    __syncthreads();
    int n = blockIdx.x * 256 + tid;
    if (n >= NN) return;
    int ty = types[n], pp = pos[n];
    float z[32];
#pragma unroll
    for (int j = 0; j < 16; j++) z[j] = W1[ty * 16 + j] + b1[j];
#pragma unroll
    for (int j = 0; j < 16; j++) z[16 + j] = W2[pp * 16 + j] + b2[j];
    float dn = dis[n];
    uint2 o[4];
#pragma unroll
    for (int q = 0; q < 4; q++) {
        float hv[4];
#pragma unroll
        for (int m = 0; m < 4; m++) {
            float a = 0.0f;
#pragma unroll
            for (int k = 0; k < 32; k++) a += z[k] * sW[k * 16 + q * 4 + m];
            hv[m] = a * dn;
        }
        o[q] = pack4(hv[0], hv[1], hv[2], hv[3]);
    }
#pragma unroll
    for (int q = 0; q < 4; q++) hs[(size_t)n * 4 + q] = o[q];
}

// ---- fused aggregate + (transform | pool): 4 threads per node ----
// Round-0 structure verbatim (proven 85.4us); only the edge gathers are
// swapped to L1-bypass loads (sc0) to escape the per-CU L1 miss-queue cap.
template <int RELU, int FUSE_POOL>
__global__ void agg_tf(const uint2* __restrict__ hs, const int* __restrict__ srcs,
                       const int* __restrict__ offs, const int* __restrict__ cnt,
                       const float* __restrict__ dis, const float* __restrict__ bias,
                       const float* __restrict__ Wn, uint2* __restrict__ hs_out,
                       const int* __restrict__ batch,
                       float* __restrict__ pool, int* __restrict__ gcnt) {
    __shared__ float sW[256];
    int tid = threadIdx.x;
    if (!FUSE_POOL) {
        sW[tid] = Wn[tid];
        __syncthreads();
    }
    int gid = blockIdx.x * 256 + tid;
    int n = gid >> 2, q = gid & 3;
    if (n >= NN) return;
    int beg = offs[n], deg = cnt[n];
    float dn = dis[n];
    float4 acc = make_float4(0.f, 0.f, 0.f, 0.f);
    int i = 0;
    for (; i + 4 <= deg; i += 4) {
        int s0 = srcs[beg + i + 0];
        int s1 = srcs[beg + i + 1];
        int s2 = srcs[beg + i + 2];
        int s3 = srcs[beg + i + 3];
        uint2 a0 = ld_bypass(&hs[(size_t)s0 * 4 + q]);
        uint2 a1 = ld_bypass(&hs[(size_t)s1 * 4 + q]);
        uint2 a2 = ld_bypass(&hs[(size_t)s2 * 4 + q]);
        uint2 a3 = ld_bypass(&hs[(size_t)s3 * 4 + q]);
        acc_u2(acc, a0); acc_u2(acc, a1); acc_u2(acc, a2); acc_u2(acc, a3);
    }
    for (; i < deg; i++) {
        int s = srcs[beg + i];
        acc_u2(acc, ld_bypass(&hs[(size_t)s * 4 + q]));
    }
    acc_u2(acc, hs[(size_t)n * 4 + q]);   // self loop (hs = h*dis, self coef dn*dn)
    float4 b4 = ((const float4*)bias)[q];
    acc.x = fmaf(acc.x, dn, b4.x);
    acc.y = fmaf(acc.y, dn, b4.y);
    acc.z = fmaf(acc.z, dn, b4.z);
    acc.w = fmaf(acc.w, dn, b4.w);
    if (RELU) {
        acc.x = fmaxf(acc.x, 0.f); acc.y = fmaxf(acc.y, 0.f);
        acc.z = fmaxf(acc.z, 0.f); acc.w = fmaxf(acc.w, 0.f);
    }
    if (FUSE_POOL) {
        float4 w4 = ((const float4*)Wn)[q];
        float s = acc.x * w4.x + acc.y * w4.y + acc.z * w4.z + acc.w * w4.w;
        s += __shfl_xor(s, 1);
        s += __shfl_xor(s, 2);
        if (q == 0) {
            int g = batch[n];
            atomicAdd(&pool[g], s);
            atomicAdd(&gcnt[g], 1);
        }
    } else {
        // exchange quad features, compute z @ Wn for this thread's 4 outputs
        float4 vals[4];
        vals[0] = acc;
        vals[1] = shfl_xor4(acc, 1);
        vals[2] = shfl_xor4(acc, 2);
        vals[3] = shfl_xor4(acc, 3);
        const float4* sW4 = (const float4*)sW;
        float4 hv = make_float4(0.f, 0.f, 0.f, 0.f);
#pragma unroll
        for (int m = 0; m < 4; m++) {
            float4 v = vals[m];
            int rb = (q ^ m) << 2;
            float4 w;
            w = sW4[(rb + 0) * 4 + q];
            hv.x += v.x * w.x; hv.y += v.x * w.y; hv.z += v.x * w.z; hv.w += v.x * w.w;
            w = sW4[(rb + 1) * 4 + q];
            hv.x += v.y * w.x; hv.y += v.y * w.y; hv.z += v.y * w.z; hv.w += v.y * w.w;
            w = sW4[(rb + 2) * 4 + q];
            hv.x += v.z * w.x; hv.y += v.z * w.y; hv.z += v.z * w.z; hv.w += v.z * w.w;
            w = sW4[(rb + 3) * 4 + q];
            hv.x += v.w * w.x; hv.y += v.w * w.y; hv.z += v.w * w.z; hv.w += v.w * w.w;
        }
        hs_out[(size_t)n * 4 + q] = pack4(hv.x * dn, hv.y * dn, hv.z * dn, hv.w * dn);
    }
}

__global__ void finalize(const float* __restrict__ pool, const int* __restrict__ gcnt,
                         const float* __restrict__ bo, float* __restrict__ out) {
    int g = blockIdx.x * 256 + threadIdx.x;
    if (g < NG) {
        float c = fmaxf((float)gcnt[g], 1.0f);
        out[g] = pool[g] / c + bo[0];
    }
}

extern "C" void kernel_launch(void* const* d_in, const int* in_sizes, int n_in,
                              void* d_out, int out_size, void* d_ws, size_t ws_size,
                              hipStream_t stream) {
    const int*   types = (const int*)d_in[0];
    const int*   pos   = (const int*)d_in[1];
    const int*   ei    = (const int*)d_in[2];   // [2, E]: src then dst
    const int*   batch = (const int*)d_in[3];
    const float* W1  = (const float*)d_in[4];
    const float* b1  = (const float*)d_in[5];
    const float* W2  = (const float*)d_in[6];
    const float* b2  = (const float*)d_in[7];
    const float* Wg0 = (const float*)d_in[8];
    const float* bg0 = (const float*)d_in[9];
    const float* Wg1 = (const float*)d_in[10];
    const float* bg1 = (const float*)d_in[11];
    const float* Wg2 = (const float*)d_in[12];
    const float* bg2 = (const float*)d_in[13];
    const float* Wo  = (const float*)d_in[14];
    const float* bo  = (const float*)d_in[15];
    float* out = (float*)d_out;

    const int* esrc = ei;
    const int* edst = ei + NE;

    // ---- workspace layout (ints) ----
    int*   bcnt  = (int*)d_ws;                   // 512  (zeroed)
    int*   bfill = bcnt + 512;                   // 512  (zeroed)
    float* pool  = (float*)(bfill + 512);        // 1024 (zeroed)
    int*   gcnt  = (int*)(pool + NG);            // 1024 (zeroed)
    int*   bbase = gcnt + NG;                    // 512
    int*   cnt   = bbase + 512;                  // NP
    int*   offs  = cnt + NP;                     // NP
    float* dis   = (float*)(offs + NP);          // NP
    int*   srcs  = (int*)(dis + NP);             // NE
    int*   part  = srcs + NE;                    // NE  (hs buffers alias this)
    uint2* hsA   = (uint2*)part;                 // NP*4 uint2 = 3.2 MB
    uint2* hsB   = (uint2*)(part + NE / 2);      // 3.2 MB (part is 12.8 MB)
    (void)ws_size; (void)n_in; (void)in_sizes; (void)out_size;

    hipMemsetAsync(d_ws, 0, (size_t)(1024 + 2 * NG) * sizeof(int), stream);

    const int NB256 = (NN + 255) / 256;          // 391
    const int QB = (NN * 4 + 255) / 256;         // 1563

    hist_buckets<<<NBLK, 256, 0, stream>>>(edst, bcnt);
    scan_buckets<<<1, 512, 0, stream>>>(bcnt, bbase);
    partition<<<NBLK, 256, 0, stream>>>(esrc, edst, bbase, bfill, part);
    build_csr<<<NBUCK, 256, 0, stream>>>(part, bbase, bcnt, cnt, offs, dis, srcs);

    // layer 0 input: hs0 = (z0 @ Wg0) * dis  (fp16)
    embed_tf0<<<NB256, 256, 0, stream>>>(types, pos, W1, b1, W2, b2, Wg0, dis, hsA);
    // layer 0 agg + relu + transform Wg1 -> hs1
    agg_tf<1, 0><<<QB, 256, 0, stream>>>(hsA, srcs, offs, cnt, dis, bg0, Wg1, hsB,
                                         batch, pool, gcnt);
    // layer 1 agg + relu + transform Wg2 -> hs2
    agg_tf<1, 0><<<QB, 256, 0, stream>>>(hsB, srcs, offs, cnt, dis, bg1, Wg2, hsA,
                                         batch, pool, gcnt);
    // layer 2 agg (no relu) + Wo dot + pool
    agg_tf<0, 1><<<QB, 256, 0, stream>>>(hsA, srcs, offs, cnt, dis, bg2, Wo, hsB /*unused*/,
                                         batch, pool, gcnt);

    finalize<<<(NG + 255) / 256, 256, 0, stream>>>(pool, gcnt, bo, out);
}

// Round 10
// 325.754 us; speedup vs baseline: 3.5833x; 1.0188x over previous
//
#include <hip/hip_runtime.h>
#include <hip/hip_fp16.h>

#define NN 100000
#define NE 3200000
#define NG 1024
#define NP 100352            // NN padded to multiple of 256
#define NBUCK 391            // ceil(NN/256) buckets of 256 dst nodes
#define NBLK 256
#define CHUNK ((NE + NBLK - 1) / NBLK)
#define WINCAP 12288

// ---------- fp16 pack/unpack helpers ----------
static __device__ inline void acc_u2(float4& acc, uint2 u) {
    __half2* ph = reinterpret_cast<__half2*>(&u);
    float2 lo = __half22float2(ph[0]);
    float2 hi = __half22float2(ph[1]);
    acc.x += lo.x; acc.y += lo.y; acc.z += hi.x; acc.w += hi.y;
}
static __device__ inline uint2 pack4(float a, float b, float c, float d) {
    __half2 lo = __floats2half2_rn(a, b);
    __half2 hi = __floats2half2_rn(c, d);
    uint2 u;
    u.x = *reinterpret_cast<unsigned int*>(&lo);
    u.y = *reinterpret_cast<unsigned int*>(&hi);
    return u;
}
static __device__ inline float4 shfl_xor4(float4 v, int m) {
    float4 r;
    r.x = __shfl_xor(v.x, m); r.y = __shfl_xor(v.y, m);
    r.z = __shfl_xor(v.z, m); r.w = __shfl_xor(v.w, m);
    return r;
}

// ---- k1: per-bucket edge histogram ----
__global__ void hist_buckets(const int* __restrict__ dst, int* __restrict__ bcnt) {
    __shared__ int sm[NBUCK];
    int tid = threadIdx.x;
    for (int i = tid; i < NBUCK; i += 256) sm[i] = 0;
    __syncthreads();
    int s = blockIdx.x * CHUNK, e = min(NE, s + CHUNK);
    for (int i = s + tid; i < e; i += 256) atomicAdd(&sm[dst[i] >> 8], 1);
    __syncthreads();
    for (int i = tid; i < NBUCK; i += 256)
        if (sm[i]) atomicAdd(&bcnt[i], sm[i]);
}

// ---- k2: exclusive scan of bucket counts ----
__global__ void scan_buckets(const int* __restrict__ bcnt, int* __restrict__ bbase) {
    __shared__ int tmp[512];
    int tid = threadIdx.x;
    int v = (tid < NBUCK) ? bcnt[tid] : 0;
    tmp[tid] = v;
    __syncthreads();
    for (int off = 1; off < 512; off <<= 1) {
        int t = (tid >= off) ? tmp[tid - off] : 0;
        __syncthreads();
        tmp[tid] += t;
        __syncthreads();
    }
    if (tid < NBUCK) bbase[tid] = tmp[tid] - v;
}

// ---- k3: partition edges into bucket regions, packed (dst&255)<<17 | src ----
__global__ void partition(const int* __restrict__ src, const int* __restrict__ dst,
                          const int* __restrict__ bbase, int* __restrict__ bfill,
                          int* __restrict__ part) {
    __shared__ int smh[NBUCK];
    __shared__ int smc[NBUCK];
    int tid = threadIdx.x;
    for (int i = tid; i < NBUCK; i += 256) smh[i] = 0;
    __syncthreads();
    int s = blockIdx.x * CHUNK, e = min(NE, s + CHUNK);
    for (int i = s + tid; i < e; i += 256) atomicAdd(&smh[dst[i] >> 8], 1);
    __syncthreads();
    for (int i = tid; i < NBUCK; i += 256) {
        int c = smh[i];
        smc[i] = c ? (bbase[i] + atomicAdd(&bfill[i], c)) : 0;
    }
    __syncthreads();
    for (int i = s + tid; i < e; i += 256) {
        int d = dst[i];
        int b = d >> 8;
        int p = atomicAdd(&smc[b], 1);
        part[p] = src[i] | ((d & 255) << 17);
    }
}

// ---- k4: per-bucket CSR build in LDS; also computes dis and the packed
//      per-node {class, fp16(dis)} table pk used by the layer-0 histogram agg ----
__global__ void build_csr(const int* __restrict__ part, const int* __restrict__ bbase,
                          const int* __restrict__ bcnt, const int* __restrict__ types,
                          const int* __restrict__ pos, int* __restrict__ cnt,
                          int* __restrict__ offs, float* __restrict__ dis,
                          unsigned int* __restrict__ pk, int* __restrict__ srcs) {
    __shared__ int sm_cnt[256];
    __shared__ int sm_off[256];
    __shared__ int sm_cur[256];
    __shared__ int sm_win[WINCAP];
    int b = blockIdx.x, tid = threadIdx.x;
    int base = bbase[b], m = bcnt[b];
    sm_cnt[tid] = 0;
    __syncthreads();
    for (int i = tid; i < m; i += 256) atomicAdd(&sm_cnt[part[base + i] >> 17], 1);
    __syncthreads();
    int v = sm_cnt[tid];
    sm_off[tid] = v;
    __syncthreads();
    for (int off = 1; off < 256; off <<= 1) {
        int t = (tid >= off) ? sm_off[tid - off] : 0;
        __syncthreads();
        sm_off[tid] += t;
        __syncthreads();
    }
    int excl = sm_off[tid] - v;
    int n = b * 256 + tid;
    if (n < NN) {
        cnt[n] = v;
        offs[n] = base + excl;
        float dv = rsqrtf((float)v + 1.0f);
        dis[n] = dv;
        int cls = types[n] * 3 + pos[n];
        __half hd = __float2half_rn(dv);
        pk[n] = ((unsigned int)cls << 16) | (unsigned int)__half_as_ushort(hd);
    }
    sm_cur[tid] = excl;
    __syncthreads();
    if (m <= WINCAP) {
        for (int i = tid; i < m; i += 256) {
            int p = part[base + i];
            int l = atomicAdd(&sm_cur[p >> 17], 1);
            sm_win[l] = p & 0x1FFFF;
        }
        __syncthreads();
        for (int i = tid; i < m; i += 256) srcs[base + i] = sm_win[i];
    } else {
        for (int i = tid; i < m; i += 256) {
            int p = part[base + i];
            int l = atomicAdd(&sm_cur[p >> 17], 1);
            srcs[base + l] = p & 0x1FFFF;
        }
    }
}

// ---- layer 0 fused: 9-class dis-histogram agg + (agg9@V) + bias + relu + @Wg1 ----
// Rank-9 structure: z0[n] depends only on (types,pos) in 3x3, so
// hs0[src] = dis[src] * V[class(src)] with V = E @ Wg0 (9x16, built in LDS).
// Per edge we gather only 4B (pk = {class,fp16 dis}) from a 400KB L2-resident
// table: random bytes drop 102.4 -> 12.8 MB (rounds 0-9 showed random BYTES,
// not requests/occupancy/L1, are the gather wall).
// 2 threads per node: h = gid&1 walks half the edge list; fold via shfl.
__global__ void agg0_tf(const unsigned int* __restrict__ pk,
                        const int* __restrict__ srcs, const int* __restrict__ offs,
                        const int* __restrict__ cnt, const float* __restrict__ dis,
                        const float* __restrict__ W1, const float* __restrict__ b1,
                        const float* __restrict__ W2, const float* __restrict__ b2,
                        const float* __restrict__ Wg0, const float* __restrict__ bg0,
                        const float* __restrict__ Wg1, uint2* __restrict__ hs_out) {
    __shared__ float sV[144];     // V[c][f] = (E[c] @ Wg0)[f], c=ty*3+pp
    __shared__ float sW[256];     // Wg1
    int tid = threadIdx.x;
    sW[tid] = Wg1[tid];
    if (tid < 144) {
        int c = tid >> 4, f = tid & 15;
        int ty = c / 3, pp = c % 3;
        float a = 0.f;
#pragma unroll
        for (int k = 0; k < 16; k++) a += (W1[ty * 16 + k] + b1[k]) * Wg0[k * 16 + f];
#pragma unroll
        for (int k = 0; k < 16; k++) a += (W2[pp * 16 + k] + b2[k]) * Wg0[(16 + k) * 16 + f];
        sV[tid] = a;
    }
    __syncthreads();
    int gid = blockIdx.x * 256 + tid;
    int n = gid >> 1, h = gid & 1;
    if (n >= NN) return;
    int beg = offs[n], deg = cnt[n];
    int half = deg >> 1;
    int lo = beg + (h ? half : 0);
    int hi = beg + (h ? deg : half);

    float a0 = 0.f, a1 = 0.f, a2 = 0.f, a3 = 0.f, a4 = 0.f;
    float a5 = 0.f, a6 = 0.f, a7 = 0.f, a8 = 0.f;
#define ACCP(P)                                                       \
    do {                                                              \
        unsigned int _p = (P);                                        \
        int _c = (int)(_p >> 16);                                     \
        float _d = __half2float(__ushort_as_half((unsigned short)(_p & 0xFFFFu))); \
        a0 += (_c == 0) ? _d : 0.f;  a1 += (_c == 1) ? _d : 0.f;      \
        a2 += (_c == 2) ? _d : 0.f;  a3 += (_c == 3) ? _d : 0.f;      \
        a4 += (_c == 4) ? _d : 0.f;  a5 += (_c == 5) ? _d : 0.f;      \
        a6 += (_c == 6) ? _d : 0.f;  a7 += (_c == 7) ? _d : 0.f;      \
        a8 += (_c == 8) ? _d : 0.f;                                   \
    } while (0)
    int i = lo;
    for (; i + 4 <= hi; i += 4) {
        int s0 = srcs[i + 0];
        int s1 = srcs[i + 1];
        int s2 = srcs[i + 2];
        int s3 = srcs[i + 3];
        unsigned int p0 = pk[s0];
        unsigned int p1 = pk[s1];
        unsigned int p2 = pk[s2];
        unsigned int p3 = pk[s3];
        ACCP(p0); ACCP(p1); ACCP(p2); ACCP(p3);
    }
    for (; i < hi; i++) ACCP(pk[srcs[i]]);

    // fold the two edge-halves (lanes gid and gid^1 share the node)
    a0 += __shfl_xor(a0, 1); a1 += __shfl_xor(a1, 1); a2 += __shfl_xor(a2, 1);
    a3 += __shfl_xor(a3, 1); a4 += __shfl_xor(a4, 1); a5 += __shfl_xor(a5, 1);
    a6 += __shfl_xor(a6, 1); a7 += __shfl_xor(a7, 1); a8 += __shfl_xor(a8, 1);
    ACCP(pk[n]);              // self loop (both lanes, identical)
#undef ACCP

    float dn = dis[n];
    float acc[9] = {a0, a1, a2, a3, a4, a5, a6, a7, a8};
    float pre[16];
#pragma unroll
    for (int f = 0; f < 16; f++) {
        float a = 0.f;
#pragma unroll
        for (int c = 0; c < 9; c++) a += acc[c] * sV[c * 16 + f];
        a = fmaf(a, dn, bg0[f]);
        pre[f] = fmaxf(a, 0.f);   // relu
    }
    if (h == 0) {
        float hv[16];
#pragma unroll
        for (int f2 = 0; f2 < 16; f2++) hv[f2] = 0.f;
#pragma unroll
        for (int f = 0; f < 16; f++) {
            float z = pre[f];
#pragma unroll
            for (int f2 = 0; f2 < 16; f2++) hv[f2] += z * sW[f * 16 + f2];
        }
        uint2* op = hs_out + (size_t)n * 4;
#pragma unroll
        for (int q = 0; q < 4; q++)
            op[q] = pack4(hv[q * 4] * dn, hv[q * 4 + 1] * dn,
                          hv[q * 4 + 2] * dn, hv[q * 4 + 3] * dn);
    }
}

// ---- fused aggregate + (transform | pool): 4 threads per node (round-0 verbatim) ----
template <int RELU, int FUSE_POOL>
__global__ void agg_tf(const uint2* __restrict__ hs, const int* __restrict__ srcs,
                       const int* __restrict__ offs, const int* __restrict__ cnt,
                       const float* __restrict__ dis, const float* __restrict__ bias,
                       const float* __restrict__ Wn, uint2* __restrict__ hs_out,
                       const int* __restrict__ batch,
                       float* __restrict__ pool, int* __restrict__ gcnt) {
    __shared__ float sW[256];
    int tid = threadIdx.x;
    if (!FUSE_POOL) {
        sW[tid] = Wn[tid];
        __syncthreads();
    }
    int gid = blockIdx.x * 256 + tid;
    int n = gid >> 2, q = gid & 3;
    if (n >= NN) return;
    int beg = offs[n], deg = cnt[n];
    float dn = dis[n];
    float4 acc = make_float4(0.f, 0.f, 0.f, 0.f);
    int i = 0;
    for (; i + 4 <= deg; i += 4) {
        int s0 = srcs[beg + i + 0];
        int s1 = srcs[beg + i + 1];
        int s2 = srcs[beg + i + 2];
        int s3 = srcs[beg + i + 3];
        uint2 a0 = hs[(size_t)s0 * 4 + q];
        uint2 a1 = hs[(size_t)s1 * 4 + q];
        uint2 a2 = hs[(size_t)s2 * 4 + q];
        uint2 a3 = hs[(size_t)s3 * 4 + q];
        acc_u2(acc, a0); acc_u2(acc, a1); acc_u2(acc, a2); acc_u2(acc, a3);
    }
    for (; i < deg; i++) {
        int s = srcs[beg + i];
        acc_u2(acc, hs[(size_t)s * 4 + q]);
    }
    acc_u2(acc, hs[(size_t)n * 4 + q]);   // self loop (hs = h*dis, self coef dn*dn)
    float4 b4 = ((const float4*)bias)[q];
    acc.x = fmaf(acc.x, dn, b4.x);
    acc.y = fmaf(acc.y, dn, b4.y);
    acc.z = fmaf(acc.z, dn, b4.z);
    acc.w = fmaf(acc.w, dn, b4.w);
    if (RELU) {
        acc.x = fmaxf(acc.x, 0.f); acc.y = fmaxf(acc.y, 0.f);
        acc.z = fmaxf(acc.z, 0.f); acc.w = fmaxf(acc.w, 0.f);
    }
    if (FUSE_POOL) {
        float4 w4 = ((const float4*)Wn)[q];
        float s = acc.x * w4.x + acc.y * w4.y + acc.z * w4.z + acc.w * w4.w;
        s += __shfl_xor(s, 1);
        s += __shfl_xor(s, 2);
        if (q == 0) {
            int g = batch[n];
            atomicAdd(&pool[g], s);
            atomicAdd(&gcnt[g], 1);
        }
    } else {
        float4 vals[4];
        vals[0] = acc;
        vals[1] = shfl_xor4(acc, 1);
        vals[2] = shfl_xor4(acc, 2);
        vals[3] = shfl_xor4(acc, 3);
        const float4* sW4 = (const float4*)sW;
        float4 hv = make_float4(0.f, 0.f, 0.f, 0.f);
#pragma unroll
        for (int m = 0; m < 4; m++) {
            float4 v = vals[m];
            int rb = (q ^ m) << 2;
            float4 w;
            w = sW4[(rb + 0) * 4 + q];
            hv.x += v.x * w.x; hv.y += v.x * w.y; hv.z += v.x * w.z; hv.w += v.x * w.w;
            w = sW4[(rb + 1) * 4 + q];
            hv.x += v.y * w.x; hv.y += v.y * w.y; hv.z += v.y * w.z; hv.w += v.y * w.w;
            w = sW4[(rb + 2) * 4 + q];
            hv.x += v.z * w.x; hv.y += v.z * w.y; hv.z += v.z * w.z; hv.w += v.z * w.w;
            w = sW4[(rb + 3) * 4 + q];
            hv.x += v.w * w.x; hv.y += v.w * w.y; hv.z += v.w * w.z; hv.w += v.w * w.w;
        }
        hs_out[(size_t)n * 4 + q] = pack4(hv.x * dn, hv.y * dn, hv.z * dn, hv.w * dn);
    }
}

__global__ void finalize(const float* __restrict__ pool, const int* __restrict__ gcnt,
                         const float* __restrict__ bo, float* __restrict__ out) {
    int g = blockIdx.x * 256 + threadIdx.x;
    if (g < NG) {
        float c = fmaxf((float)gcnt[g], 1.0f);
        out[g] = pool[g] / c + bo[0];
    }
}

extern "C" void kernel_launch(void* const* d_in, const int* in_sizes, int n_in,
                              void* d_out, int out_size, void* d_ws, size_t ws_size,
                              hipStream_t stream) {
    const int*   types = (const int*)d_in[0];
    const int*   pos   = (const int*)d_in[1];
    const int*   ei    = (const int*)d_in[2];   // [2, E]: src then dst
    const int*   batch = (const int*)d_in[3];
    const float* W1  = (const float*)d_in[4];
    const float* b1  = (const float*)d_in[5];
    const float* W2  = (const float*)d_in[6];
    const float* b2  = (const float*)d_in[7];
    const float* Wg0 = (const float*)d_in[8];
    const float* bg0 = (const float*)d_in[9];
    const float* Wg1 = (const float*)d_in[10];
    const float* bg1 = (const float*)d_in[11];
    const float* Wg2 = (const float*)d_in[12];
    const float* bg2 = (const float*)d_in[13];
    const float* Wo  = (const float*)d_in[14];
    const float* bo  = (const float*)d_in[15];
    float* out = (float*)d_out;

    const int* esrc = ei;
    const int* edst = ei + NE;

    // ---- workspace layout (ints) ----
    int*   bcnt  = (int*)d_ws;                   // 512  (zeroed)
    int*   bfill = bcnt + 512;                   // 512  (zeroed)
    float* pool  = (float*)(bfill + 512);        // 1024 (zeroed)
    int*   gcnt  = (int*)(pool + NG);            // 1024 (zeroed)
    int*   bbase = gcnt + NG;                    // 512
    int*   cnt   = bbase + 512;                  // NP
    int*   offs  = cnt + NP;                     // NP
    float* dis   = (float*)(offs + NP);          // NP
    unsigned int* pk = (unsigned int*)(dis + NP);// NP  ({class,fp16 dis} table)
    int*   srcs  = (int*)(pk + NP);              // NE  (16B-aligned)
    int*   part  = srcs + NE;                    // NE  (hs buffers alias this)
    uint2* hsA   = (uint2*)part;                 // NP*4 uint2 = 3.2 MB
    uint2* hsB   = (uint2*)(part + NE / 2);      // 3.2 MB (part is 12.8 MB)
    (void)ws_size; (void)n_in; (void)in_sizes; (void)out_size;

    hipMemsetAsync(d_ws, 0, (size_t)(1024 + 2 * NG) * sizeof(int), stream);

    const int QB  = (NN * 4 + 255) / 256;        // 1563
    const int QB2 = (NN * 2 + 255) / 256;        // 782

    hist_buckets<<<NBLK, 256, 0, stream>>>(edst, bcnt);
    scan_buckets<<<1, 512, 0, stream>>>(bcnt, bbase);
    partition<<<NBLK, 256, 0, stream>>>(esrc, edst, bbase, bfill, part);
    build_csr<<<NBUCK, 256, 0, stream>>>(part, bbase, bcnt, types, pos,
                                         cnt, offs, dis, pk, srcs);

    // layer 0 (fused rank-9): 4B/edge pk gather -> hs1 = (relu(...)@Wg1)*dis
    agg0_tf<<<QB2, 256, 0, stream>>>(pk, srcs, offs, cnt, dis, W1, b1, W2, b2,
                                     Wg0, bg0, Wg1, hsA);
    // layer 1 agg + relu + transform Wg2 -> hs2
    agg_tf<1, 0><<<QB, 256, 0, stream>>>(hsA, srcs, offs, cnt, dis, bg1, Wg2, hsB,
                                         batch, pool, gcnt);
    // layer 2 agg (no relu) + Wo dot + pool
    agg_tf<0, 1><<<QB, 256, 0, stream>>>(hsB, srcs, offs, cnt, dis, bg2, Wo, hsA /*unused*/,
                                         batch, pool, gcnt);

    finalize<<<(NG + 255) / 256, 256, 0, stream>>>(pool, gcnt, bo, out);
}